// Round 6
// baseline (1402.043 us; speedup 1.0000x reference)
//
#include <hip/hip_runtime.h>
#include <hip/hip_bf16.h>

typedef __bf16 bf16;
typedef __bf16 bf16x4 __attribute__((ext_vector_type(4)));
typedef __bf16 bf16x8 __attribute__((ext_vector_type(8)));
typedef float f32x4 __attribute__((ext_vector_type(4)));

#define NPIX 4096

// ---------------------------------------------------------------------------
// f32 -> bf16 conversion of the 8 GEMM weight tensors (x handled by xpose).
// ---------------------------------------------------------------------------
struct CvtArgs {
    const float* src[8];
    bf16* dst[8];
    long gpre[9];
};

__global__ __launch_bounds__(256) void cvt_kernel(CvtArgs a, long totalGroups)
{
    long g = (long)blockIdx.x * 256 + threadIdx.x;
    if (g >= totalGroups) return;
    int lo = 0, hi = 7;
    while (lo < hi) { int mid = (lo + hi) >> 1; if (g >= a.gpre[mid + 1]) lo = mid + 1; else hi = mid; }
    long off = (g - a.gpre[lo]) << 3;
    const float* s = a.src[lo] + off;
    float4 v0 = *(const float4*)s;
    float4 v1 = *(const float4*)(s + 4);
    bf16x8 o;
    o[0] = (bf16)v0.x; o[1] = (bf16)v0.y; o[2] = (bf16)v0.z; o[3] = (bf16)v0.w;
    o[4] = (bf16)v1.x; o[5] = (bf16)v1.y; o[6] = (bf16)v1.z; o[7] = (bf16)v1.w;
    *(bf16x8*)(a.dst[lo] + off) = o;
}

// ---------------------------------------------------------------------------
// x (B, 384, 4096) f32  ->  XT (B, 4096, 384) bf16.  64x64 LDS tile transpose.
// grid (64, 6, 8), block 256.
// ---------------------------------------------------------------------------
__global__ __launch_bounds__(256) void xpose_in_kernel(
    const float* __restrict__ x, bf16* __restrict__ XT)
{
    __shared__ bf16 Lt[64][72];
    const int n0 = blockIdx.x << 6, c0 = blockIdx.y << 6, b = blockIdx.z;
    const int t = threadIdx.x;
    const int rr = t >> 4, q4 = (t & 15) << 2;
    #pragma unroll
    for (int it = 0; it < 4; it++) {
        int ci = rr + it * 16;
        float4 v = *(const float4*)(x + ((long)(b * 384 + c0 + ci) << 12) + n0 + q4);
        Lt[ci][q4 + 0] = (bf16)v.x; Lt[ci][q4 + 1] = (bf16)v.y;
        Lt[ci][q4 + 2] = (bf16)v.z; Lt[ci][q4 + 3] = (bf16)v.w;
    }
    __syncthreads();
    #pragma unroll
    for (int it = 0; it < 4; it++) {
        int ni = rr + it * 16;
        bf16x4 o;
        #pragma unroll
        for (int e = 0; e < 4; e++) o[e] = Lt[q4 + e][ni];
        *(bf16x4*)(XT + ((long)(b * NPIX + n0 + ni)) * 384 + c0 + q4) = o;
    }
}

// ---------------------------------------------------------------------------
// PRJ (B, 4096, 384) bf16 -> d_out (B, 384, 4096) f32.
// ---------------------------------------------------------------------------
__global__ __launch_bounds__(256) void xpose_out_kernel(
    const bf16* __restrict__ PRJ, float* __restrict__ outp)
{
    __shared__ bf16 Lt[64][72];
    const int n0 = blockIdx.x << 6, c0 = blockIdx.y << 6, b = blockIdx.z;
    const int t = threadIdx.x;
    const int rr = t >> 4, q4 = (t & 15) << 2;
    #pragma unroll
    for (int it = 0; it < 4; it++) {
        int ni = rr + it * 16;
        bf16x4 v = *(const bf16x4*)(PRJ + ((long)(b * NPIX + n0 + ni)) * 384 + c0 + q4);
        #pragma unroll
        for (int e = 0; e < 4; e++) Lt[ni][q4 + e] = v[e];
    }
    __syncthreads();
    #pragma unroll
    for (int it = 0; it < 4; it++) {
        int ci = rr + it * 16;
        float4 f;
        f.x = (float)Lt[q4 + 0][ci]; f.y = (float)Lt[q4 + 1][ci];
        f.z = (float)Lt[q4 + 2][ci]; f.w = (float)Lt[q4 + 3][ci];
        *(float4*)(outp + ((long)(b * 384 + c0 + ci) << 12) + n0 + q4) = f;
    }
}

// ---------------------------------------------------------------------------
// NT-GEMM, 128n x 128m tile: OT[b][n][m] = XT[b][n][:].W[m][:] + bias[m].
// Both fragments direct-from-global b128 (k-contiguous). No LDS, no barriers.
// grid 1D: blockIdx&7 = batch (XCD swizzle), then nTile, then mTile.
// ---------------------------------------------------------------------------
__global__ __launch_bounds__(256) void gemm_nt128_kernel(
    const bf16* __restrict__ Xg, long xBatch, int xRow,
    const bf16* __restrict__ Wg, int K,
    const float* __restrict__ bias, bf16* __restrict__ Og,
    long oBatch, int oRow, int nTiles)
{
    const int t = threadIdx.x;
    const int lin = blockIdx.x;
    const int b = lin & 7;
    const int rest = lin >> 3;
    const int nBase = (rest % nTiles) << 7;
    const int mBase = (rest / nTiles) << 7;
    const int lane = t & 63, wv = t >> 6;
    const int nOff = (wv & 1) << 6, mOff = (wv >> 1) << 6;
    const int lr = lane & 15, qd = lane >> 4;
    const bf16* Ab = Xg + (long)b * xBatch;

    f32x4 acc[4][4] = {};
    for (int k0 = 0; k0 < K; k0 += 32) {
        bf16x8 a[4], bb[4];
        #pragma unroll
        for (int i = 0; i < 4; i++)
            a[i] = *(const bf16x8*)(Ab + (long)(nBase + nOff + i * 16 + lr) * xRow + k0 + qd * 8);
        #pragma unroll
        for (int j = 0; j < 4; j++)
            bb[j] = *(const bf16x8*)(Wg + (long)(mBase + mOff + j * 16 + lr) * K + k0 + qd * 8);
        #pragma unroll
        for (int i = 0; i < 4; i++)
            #pragma unroll
            for (int j = 0; j < 4; j++)
                acc[i][j] = __builtin_amdgcn_mfma_f32_16x16x32_bf16(a[i], bb[j], acc[i][j], 0, 0, 0);
    }

    float bj[4];
    #pragma unroll
    for (int j = 0; j < 4; j++) bj[j] = bias ? bias[mBase + mOff + j * 16 + lr] : 0.f;

    bf16* Ob = Og + (long)b * oBatch;
    #pragma unroll
    for (int i = 0; i < 4; i++)
        #pragma unroll
        for (int r = 0; r < 4; r++) {
            long rowOff = (long)(nBase + nOff + i * 16 + qd * 4 + r) * oRow;
            #pragma unroll
            for (int j = 0; j < 4; j++)
                Ob[rowOff + mBase + mOff + j * 16 + lr] = (bf16)(acc[i][j][r] + bj[j]);
        }
}

// ---------------------------------------------------------------------------
// NT-GEMM, 128n x 64m tile (M % 64 == 0). 4 waves split n (32 each).
// ---------------------------------------------------------------------------
__global__ __launch_bounds__(256) void gemm_nt64_kernel(
    const bf16* __restrict__ Xg, long xBatch, int xRow,
    const bf16* __restrict__ Wg, int K,
    const float* __restrict__ bias, bf16* __restrict__ Og,
    long oBatch, int oRow, int nTiles)
{
    const int t = threadIdx.x;
    const int lin = blockIdx.x;
    const int b = lin & 7;
    const int rest = lin >> 3;
    const int nBase = (rest % nTiles) << 7;
    const int mBase = (rest / nTiles) << 6;
    const int lane = t & 63, wv = t >> 6;
    const int nOff = wv << 5;
    const int lr = lane & 15, qd = lane >> 4;
    const bf16* Ab = Xg + (long)b * xBatch;

    f32x4 acc[2][4] = {};
    for (int k0 = 0; k0 < K; k0 += 32) {
        bf16x8 a[2], bb[4];
        #pragma unroll
        for (int i = 0; i < 2; i++)
            a[i] = *(const bf16x8*)(Ab + (long)(nBase + nOff + i * 16 + lr) * xRow + k0 + qd * 8);
        #pragma unroll
        for (int j = 0; j < 4; j++)
            bb[j] = *(const bf16x8*)(Wg + (long)(mBase + j * 16 + lr) * K + k0 + qd * 8);
        #pragma unroll
        for (int i = 0; i < 2; i++)
            #pragma unroll
            for (int j = 0; j < 4; j++)
                acc[i][j] = __builtin_amdgcn_mfma_f32_16x16x32_bf16(a[i], bb[j], acc[i][j], 0, 0, 0);
    }

    float bj[4];
    #pragma unroll
    for (int j = 0; j < 4; j++) bj[j] = bias ? bias[mBase + j * 16 + lr] : 0.f;

    bf16* Ob = Og + (long)b * oBatch;
    #pragma unroll
    for (int i = 0; i < 2; i++)
        #pragma unroll
        for (int r = 0; r < 4; r++) {
            long rowOff = (long)(nBase + nOff + i * 16 + qd * 4 + r) * oRow;
            #pragma unroll
            for (int j = 0; j < 4; j++)
                Ob[rowOff + mBase + j * 16 + lr] = (bf16)(acc[i][j][r] + bj[j]);
        }
}

// ---------------------------------------------------------------------------
// invn[b][c] (c<768: q,k channels) = 1/max(||QKVT[:, c]||, 1e-12). grid (12,B).
// ---------------------------------------------------------------------------
__global__ __launch_bounds__(256) void rownorm_kernel(
    const bf16* __restrict__ qkvt, float* __restrict__ invn)
{
    const int b = blockIdx.y;
    const int c = (blockIdx.x << 6) + (threadIdx.x & 63);
    const int g = threadIdx.x >> 6;
    float s = 0.f;
    const bf16* base = qkvt + (long)b * NPIX * 1152 + c;
    for (int n = g; n < NPIX; n += 4) {
        float v = (float)base[(long)n * 1152];
        s += v * v;
    }
    __shared__ float red[256];
    red[threadIdx.x] = s;
    __syncthreads();
    if (threadIdx.x < 64) {
        float tot = red[threadIdx.x] + red[threadIdx.x + 64] + red[threadIdx.x + 128] + red[threadIdx.x + 192];
        invn[b * 768 + (blockIdx.x << 6) + threadIdx.x] = 1.0f / fmaxf(sqrtf(tot), 1e-12f);
    }
}

// ---------------------------------------------------------------------------
// Attention logits partials via LDS-transposed q,k tiles.
// grid (4, 64): kc in [0,4), bh. Block stages 256 n x 48 c for q and k,
// each wave MFMAs its own 64-n sub-chunk; 4 stage-iters; 16 slots total.
// part[bh][slot][48*48] f32.
// ---------------------------------------------------------------------------
__global__ __launch_bounds__(256) void attn_logits_kernel(
    const bf16* __restrict__ qkvt, float* __restrict__ part)
{
    __shared__ bf16 QK[96 * 264];   // rows 0..47 q, 48..95 k; cols n (pad 264)
    const int kc = blockIdx.x;
    const int bh = blockIdx.y;
    const int b = bh >> 3, h = bh & 7;
    const int t = threadIdx.x, lane = t & 63, wv = t >> 6;
    const int lr = lane & 15, qd = lane >> 4;
    const long qbase = (long)b * NPIX * 1152 + h * 48;

    f32x4 acc[3][3] = {};
    for (int it = 0; it < 4; it++) {
        const int nBase = kc * 1024 + it * 256;
        __syncthreads();   // protect previous iter's LDS reads
        for (int cc = 0; cc < 12; cc++) {
            int chunk = cc * 256 + t;            // 0..3071
            int which = chunk >= 1536;           // 0=q, 1=k
            int r2 = chunk - which * 1536;
            int n_l = r2 / 6, cgi = r2 - n_l * 6;
            bf16x8 v = *(const bf16x8*)(qkvt + qbase + (long)(nBase + n_l) * 1152 + which * 384 + cgi * 8);
            bf16* dst = &QK[(which * 48 + cgi * 8) * 264 + n_l];
            #pragma unroll
            for (int e = 0; e < 8; e++) dst[e * 264] = v[e];
        }
        __syncthreads();
        const int n0 = wv << 6;
        #pragma unroll
        for (int ks = 0; ks < 2; ks++) {
            bf16x8 a[3], bb[3];
            #pragma unroll
            for (int i = 0; i < 3; i++) {
                a[i]  = *(const bf16x8*)(&QK[(i * 16 + lr) * 264 + n0 + ks * 32 + qd * 8]);
                bb[i] = *(const bf16x8*)(&QK[(48 + i * 16 + lr) * 264 + n0 + ks * 32 + qd * 8]);
            }
            #pragma unroll
            for (int i = 0; i < 3; i++)
                #pragma unroll
                for (int j = 0; j < 3; j++)
                    acc[i][j] = __builtin_amdgcn_mfma_f32_16x16x32_bf16(a[i], bb[j], acc[i][j], 0, 0, 0);
        }
    }
    float* pp = part + ((long)bh * 16 + kc * 4 + wv) * 2304;
    #pragma unroll
    for (int i = 0; i < 3; i++)
        #pragma unroll
        for (int j = 0; j < 3; j++)
            #pragma unroll
            for (int r = 0; r < 4; r++)
                pp[(i * 16 + qd * 4 + r) * 48 + j * 16 + lr] = acc[i][j][r];
}

// ---------------------------------------------------------------------------
// Sum 16 partial slots, scale by invq*invk*temp, softmax over e -> attn f32.
// ---------------------------------------------------------------------------
__global__ __launch_bounds__(256) void attn_softmax_kernel(
    const float* __restrict__ part, const float* __restrict__ invn,
    const float* __restrict__ temp, float* __restrict__ attn)
{
    __shared__ float sl[2304];
    const int bh = blockIdx.x, b = bh >> 3, h = bh & 7;
    const int t = threadIdx.x;
    const float tmp = temp[h];
    for (int idx = t; idx < 2304; idx += 256) {
        float s = 0.f;
        #pragma unroll
        for (int p = 0; p < 16; p++) s += part[((long)bh * 16 + p) * 2304 + idx];
        int d = idx / 48, e = idx - d * 48;
        s *= invn[b * 768 + h * 48 + d] * invn[b * 768 + 384 + h * 48 + e] * tmp;
        sl[idx] = s;
    }
    __syncthreads();
    if (t < 48) {
        float m = -1e30f;
        #pragma unroll
        for (int e = 0; e < 48; e++) m = fmaxf(m, sl[t * 48 + e]);
        float ex[48]; float sum = 0.f;
        #pragma unroll
        for (int e = 0; e < 48; e++) { ex[e] = expf(sl[t * 48 + e] - m); sum += ex[e]; }
        float inv = 1.0f / sum;
        #pragma unroll
        for (int e = 0; e < 48; e++) attn[(long)bh * 2304 + t * 48 + e] = ex[e] * inv;
    }
}

// ---------------------------------------------------------------------------
// at[n][h*48+d] = sum_e attn[d][e] * v[n][e].  b128 reads and writes.
// grid (16, 64).
// ---------------------------------------------------------------------------
__global__ __launch_bounds__(256) void attn_apply_kernel(
    const float* __restrict__ attn, const bf16* __restrict__ qkvt,
    bf16* __restrict__ at)
{
    __shared__ float sa[2304];
    const int bh = blockIdx.y, b = bh >> 3, h = bh & 7;
    const int t = threadIdx.x;
    for (int i = t; i < 2304; i += 256) sa[i] = attn[(long)bh * 2304 + i];
    __syncthreads();
    const int n = blockIdx.x * 256 + t;
    const bf16* vp = qkvt + ((long)(b * NPIX + n)) * 1152 + 768 + h * 48;
    float vv[48];
    #pragma unroll
    for (int cg = 0; cg < 6; cg++) {
        bf16x8 v = *(const bf16x8*)(vp + cg * 8);
        #pragma unroll
        for (int e = 0; e < 8; e++) vv[cg * 8 + e] = (float)v[e];
    }
    bf16* ap = at + ((long)(b * NPIX + n)) * 384 + h * 48;
    #pragma unroll
    for (int cg = 0; cg < 6; cg++) {
        bf16x8 o;
        #pragma unroll
        for (int dd = 0; dd < 8; dd++) {
            int d = cg * 8 + dd;
            float acc = 0.f;
            for (int e = 0; e < 48; e++) acc += sa[d * 48 + e] * vv[e];
            o[dd] = (bf16)acc;
        }
        *(bf16x8*)(ap + cg * 8) = o;
    }
}

// ---------------------------------------------------------------------------
// Depthwise 3x3, pad 1, NHWC. Thread = (pixel, 8-channel group). Weights f32
// from global (L1-hot). grid = B*4096*(CH/8)/256.
// ---------------------------------------------------------------------------
template<int CH>
__global__ __launch_bounds__(256) void dw3_kernel(
    const bf16* __restrict__ in, const float* __restrict__ wt,
    const float* __restrict__ bias, bf16* __restrict__ outp)
{
    constexpr int G = CH / 8;
    const int gid = blockIdx.x * 256 + threadIdx.x;
    const int p = gid / G, cg = gid - p * G;
    const int b = p >> 12, pix = p & 4095, y = pix >> 6, xx = pix & 63;

    float wr[9][8];
    #pragma unroll
    for (int e = 0; e < 8; e++)
        #pragma unroll
        for (int tp = 0; tp < 9; tp++)
            wr[tp][e] = wt[(cg * 8 + e) * 9 + tp];

    float acc[8];
    #pragma unroll
    for (int e = 0; e < 8; e++) acc[e] = bias[cg * 8 + e];

    const bf16* ib = in + ((long)b << 12) * CH;
    #pragma unroll
    for (int dy = -1; dy <= 1; dy++) {
        int yy = y + dy;
        if (yy < 0 || yy >= 64) continue;
        #pragma unroll
        for (int dx = -1; dx <= 1; dx++) {
            int x2 = xx + dx;
            if (x2 < 0 || x2 >= 64) continue;
            bf16x8 v = *(const bf16x8*)(ib + (long)(yy * 64 + x2) * CH + cg * 8);
            int tp = (dy + 1) * 3 + (dx + 1);
            #pragma unroll
            for (int e = 0; e < 8; e++) acc[e] += wr[tp][e] * (float)v[e];
        }
    }
    bf16x8 o;
    #pragma unroll
    for (int e = 0; e < 8; e++) o[e] = (bf16)acc[e];
    *(bf16x8*)(outp + (long)p * CH + cg * 8) = o;
}

// ---------------------------------------------------------------------------
// Depthwise 7x7, dilation 3, pad 9, CH=64, NHWC. Weights staged in LDS.
// grid = B*4096*8/256 = 1024.
// ---------------------------------------------------------------------------
__global__ __launch_bounds__(256) void dw7_kernel(
    const bf16* __restrict__ in, const float* __restrict__ wt,
    const float* __restrict__ bias, bf16* __restrict__ outp)
{
    __shared__ float wf[64 * 49];
    __shared__ float bf[64];
    for (int i = threadIdx.x; i < 64 * 49; i += 256) wf[i] = wt[i];
    if (threadIdx.x < 64) bf[threadIdx.x] = bias[threadIdx.x];
    __syncthreads();

    const int gid = blockIdx.x * 256 + threadIdx.x;
    const int cg = gid & 7, p = gid >> 3;
    const int b = p >> 12, pix = p & 4095, y = pix >> 6, xx = pix & 63;

    float acc[8];
    #pragma unroll
    for (int e = 0; e < 8; e++) acc[e] = bf[cg * 8 + e];

    const bf16* ib = in + ((long)b << 12) * 64;
    for (int i = 0; i < 7; i++) {
        int yy = y + i * 3 - 9;
        if (yy < 0 || yy >= 64) continue;
        for (int j = 0; j < 7; j++) {
            int x2 = xx + j * 3 - 9;
            if (x2 < 0 || x2 >= 64) continue;
            bf16x8 v = *(const bf16x8*)(ib + (long)(yy * 64 + x2) * 64 + cg * 8);
            int tp = i * 7 + j;
            #pragma unroll
            for (int e = 0; e < 8; e++) acc[e] += wf[(cg * 8 + e) * 49 + tp] * (float)v[e];
        }
    }
    bf16x8 o;
    #pragma unroll
    for (int e = 0; e < 8; e++) o[e] = (bf16)acc[e];
    *(bf16x8*)(outp + (long)p * 64 + cg * 8) = o;
}

// ---------------------------------------------------------------------------
// mean over n for CH channels, NHWC. grid (CH/64, B).
// ---------------------------------------------------------------------------
__global__ __launch_bounds__(256) void mean_kernel(
    const bf16* __restrict__ in, float* __restrict__ outp, int CH)
{
    const int b = blockIdx.y;
    const int c = (blockIdx.x << 6) + (threadIdx.x & 63);
    const int g = threadIdx.x >> 6;
    float s = 0.f;
    const bf16* base = in + (long)b * NPIX * CH + c;
    for (int n = g; n < NPIX; n += 4) s += (float)base[(long)n * CH];
    __shared__ float red[256];
    red[threadIdx.x] = s;
    __syncthreads();
    if (threadIdx.x < 64)
        outp[b * CH + (blockIdx.x << 6) + threadIdx.x] =
            (red[threadIdx.x] + red[threadIdx.x + 64] + red[threadIdx.x + 128] + red[threadIdx.x + 192]) * (1.0f / NPIX);
}

// ci1[b][o] = bias[o] + sum_i w[o][i]*tmean[b][i]
__global__ __launch_bounds__(64) void ci1_kernel(
    const float* __restrict__ tmean, const float* __restrict__ wt,
    const float* __restrict__ bias, float* __restrict__ ci1v)
{
    const int b = blockIdx.x, o = threadIdx.x;
    float s = bias[o];
    for (int i = 0; i < 64; i++) s += wt[o * 64 + i] * tmean[b * 64 + i];
    ci1v[b * 64 + o] = s;
}

// g[n][c] = t[n][c] * ci1[b][c] * u3[n][c]   (NHWC, CH=64)
__global__ __launch_bounds__(256) void g_eltwise_kernel(
    const bf16* __restrict__ t, const float* __restrict__ ci1v,
    const bf16* __restrict__ u3, bf16* __restrict__ g)
{
    unsigned idx = ((unsigned)blockIdx.x * 256 + threadIdx.x) << 3;
    unsigned row = idx >> 6, c0 = idx & 63;
    const float* cp = ci1v + (row >> 12) * 64 + c0;
    float4 s0 = *(const float4*)cp;
    float4 s1 = *(const float4*)(cp + 4);
    float sv[8] = {s0.x, s0.y, s0.z, s0.w, s1.x, s1.y, s1.z, s1.w};
    bf16x8 tv = *(const bf16x8*)(t + idx);
    bf16x8 uv = *(const bf16x8*)(u3 + idx);
    bf16x8 ov;
    #pragma unroll
    for (int e = 0; e < 8; e++) ov[e] = (bf16)((float)tv[e] * sv[e] * (float)uv[e]);
    *(bf16x8*)(g + idx) = ov;
}

// g2[n][c] = gelu_exact(d[n][c]) * d[n][c+96]   (NHWC, d CH=192, g2 CH=96)
__global__ __launch_bounds__(256) void gelu_mul_kernel(
    const bf16* __restrict__ dd, bf16* __restrict__ g2)
{
    unsigned idx = ((unsigned)blockIdx.x * 256 + threadIdx.x) << 3;  // over B*4096*96
    unsigned row = idx / 96, off = idx - row * 96;
    bf16x8 v1 = *(const bf16x8*)(dd + (long)row * 192 + off);
    bf16x8 v2 = *(const bf16x8*)(dd + (long)row * 192 + off + 96);
    bf16x8 ov;
    #pragma unroll
    for (int e = 0; e < 8; e++) {
        float x1 = (float)v1[e];
        float g = 0.5f * x1 * (1.0f + erff(x1 * 0.70710678118654752f));
        ov[e] = (bf16)(g * (float)v2[e]);
    }
    *(bf16x8*)(g2 + idx) = ov;
}

// at = (at + cmap)*sigmoid(smap) + convx*sigmoid(cm[b][c])   (NHWC, CH=384)
__global__ __launch_bounds__(256) void final_mix_kernel(
    bf16* __restrict__ at, const bf16* __restrict__ cmap,
    const bf16* __restrict__ smap, const bf16* __restrict__ convx,
    const float* __restrict__ cm)
{
    unsigned idx = ((unsigned)blockIdx.x * 256 + threadIdx.x) << 3;
    unsigned row = idx / 384, c0 = idx - row * 384;
    const float* cp = cm + (row >> 12) * 384 + c0;
    float4 s0 = *(const float4*)cp;
    float4 s1 = *(const float4*)(cp + 4);
    float gv[8] = {s0.x, s0.y, s0.z, s0.w, s1.x, s1.y, s1.z, s1.w};
    bf16x8 av = *(const bf16x8*)(at + idx);
    bf16x8 cv = *(const bf16x8*)(cmap + idx);
    bf16x8 sv = *(const bf16x8*)(smap + idx);
    bf16x8 xv = *(const bf16x8*)(convx + idx);
    bf16x8 ov;
    #pragma unroll
    for (int e = 0; e < 8; e++) {
        float a = (float)av[e] + (float)cv[e];
        float s = 1.0f / (1.0f + expf(-(float)sv[e]));
        float g = 1.0f / (1.0f + expf(-gv[e]));
        ov[e] = (bf16)(a * s + (float)xv[e] * g);
    }
    *(bf16x8*)(at + idx) = ov;
}

// ---------------------------------------------------------------------------
extern "C" void kernel_launch(void* const* d_in, const int* in_sizes, int n_in,
                              void* d_out, int out_size, void* d_ws, size_t ws_size,
                              hipStream_t stream)
{
    const int B = 8;
    const long NB = (long)B * NPIX;

    char* wsp = (char*)d_ws;
    size_t off = 0;
    auto alloc = [&](size_t bytes) -> char* {
        char* p = wsp + off; off += (bytes + 255) & ~(size_t)255; return p;
    };

    // bf16 weight copies: qkv_w, proj_w, dw1_w, cp_in_w, ci2c_w, cp_out_w, sp_in_w, sp_out_w
    const int cvtIdx[8] = {2, 3, 5, 9, 17, 19, 21, 25};
    bf16* wcv[8];
    CvtArgs ca;
    long gpre = 0;
    for (int i = 0; i < 8; i++) {
        int ti = cvtIdx[i];
        wcv[i] = (bf16*)alloc((size_t)in_sizes[ti] * 2);
        ca.src[i] = (const float*)d_in[ti];
        ca.dst[i] = wcv[i];
        ca.gpre[i] = gpre;
        gpre += in_sizes[ti] >> 3;
    }
    ca.gpre[8] = gpre;

    const bf16 *qkv_w = wcv[0], *proj_w = wcv[1], *dw1_w = wcv[2], *cp_in_w = wcv[3],
               *ci2c_w = wcv[4], *cp_out_w = wcv[5], *sp_in_w = wcv[6], *sp_out_w = wcv[7];

    const float* xf      = (const float*)d_in[0];
    const float* temp    = (const float*)d_in[1];
    const float* proj_b  = (const float*)d_in[4];
    const float* dw1_b   = (const float*)d_in[6];
    const float* dw2_w   = (const float*)d_in[7];
    const float* dw2_b   = (const float*)d_in[8];
    const float* cp_in_b = (const float*)d_in[10];
    const float* ci1_w   = (const float*)d_in[11];
    const float* ci1_b   = (const float*)d_in[12];
    const float* ci2a_w  = (const float*)d_in[13];
    const float* ci2a_b  = (const float*)d_in[14];
    const float* ci2b_w  = (const float*)d_in[15];
    const float* ci2b_b  = (const float*)d_in[16];
    const float* ci2c_b  = (const float*)d_in[18];
    const float* cp_out_b= (const float*)d_in[20];
    const float* sp_in_b = (const float*)d_in[22];
    const float* sp_dw_w = (const float*)d_in[23];
    const float* sp_dw_b = (const float*)d_in[24];
    const float* sp_out_b= (const float*)d_in[26];

    bf16*  XT    = (bf16*) alloc(NB * 384 * 2);
    bf16*  QKVT  = (bf16*) alloc(NB * 1152 * 2 + 256);
    bf16*  AT    = (bf16*) alloc(NB * 384 * 2);
    bf16*  CONV1 = (bf16*) alloc(NB * 384 * 2);
    bf16*  CONVX = (bf16*) alloc(NB * 384 * 2);
    bf16*  CMAP  = (bf16*) alloc(NB * 384 * 2);
    bf16*  T     = (bf16*) alloc(NB * 64 * 2);
    bf16*  U1    = (bf16*) alloc(NB * 64 * 2);
    bf16*  U2    = (bf16*) alloc(NB * 64 * 2);
    bf16*  SP    = (bf16*) alloc(NB * 192 * 2);
    bf16*  DDb   = (bf16*) alloc(NB * 192 * 2);
    float* PART  = (float*)alloc((size_t)64 * 16 * 2304 * 4);
    float* ATTN  = (float*)alloc((size_t)64 * 2304 * 4);
    float* INVN  = (float*)alloc((size_t)B * 768 * 4);
    float* TMEAN = (float*)alloc((size_t)B * 64 * 4);
    float* CI1V  = (float*)alloc((size_t)B * 64 * 4);
    float* CMv   = (float*)alloc((size_t)B * 384 * 4);
    bf16* SMAP = CONV1;   // CONV1 dead after dw3 -> CONVX
    bf16* G2   = SP;      // SP dead after sp_dw
    bf16* U3   = U1;      // U1 dead after dw7
    bf16* G    = U2;      // U2 dead after ci2c
    bf16* PRJ  = QKVT;    // QKVT dead after dw1

    // 0. weight cvt + x transpose
    cvt_kernel<<<(int)((gpre + 255) / 256), 256, 0, stream>>>(ca, gpre);
    xpose_in_kernel<<<dim3(64, 6, 8), 256, 0, stream>>>(xf, XT);

    // 1. QKVT = XT @ qkv_w^T   (B, 4096, 1152)
    gemm_nt128_kernel<<<8 * 32 * 9, 256, 0, stream>>>(
        XT, NB / B * 384, 384, qkv_w, 384, nullptr, QKVT, (long)NPIX * 1152, 1152, 32);
    // 2-5. attention
    rownorm_kernel<<<dim3(12, 8), 256, 0, stream>>>(QKVT, INVN);
    attn_logits_kernel<<<dim3(4, 64), 256, 0, stream>>>(QKVT, PART);
    attn_softmax_kernel<<<64, 256, 0, stream>>>(PART, INVN, temp, ATTN);
    attn_apply_kernel<<<dim3(16, 64), 256, 0, stream>>>(ATTN, QKVT, AT);
    // 6. conv1 = v @ dw1^T
    gemm_nt128_kernel<<<8 * 32 * 3, 256, 0, stream>>>(
        QKVT + 768, (long)NPIX * 1152, 1152, dw1_w, 384, dw1_b, CONV1, (long)NPIX * 384, 384, 32);
    // 7. conv_x = dw3x3(conv1)
    dw3_kernel<384><<<6144, 256, 0, stream>>>(CONV1, dw2_w, dw2_b, CONVX);
    // 8. t = at @ cp_in^T  (M=64)
    gemm_nt64_kernel<<<8 * 32, 256, 0, stream>>>(
        AT, (long)NPIX * 384, 384, cp_in_w, 384, cp_in_b, T, (long)NPIX * 64, 64, 32);
    // 9-10. ci1
    mean_kernel<<<dim3(1, 8), 256, 0, stream>>>(T, TMEAN, 64);
    ci1_kernel<<<8, 64, 0, stream>>>(TMEAN, ci1_w, ci1_b, CI1V);
    // 11-13. ci2 chain
    dw3_kernel<64><<<1024, 256, 0, stream>>>(T, ci2a_w, ci2a_b, U1);
    dw7_kernel<<<1024, 256, 0, stream>>>(U1, ci2b_w, ci2b_b, U2);
    gemm_nt64_kernel<<<8 * 32, 256, 0, stream>>>(
        U2, (long)NPIX * 64, 64, ci2c_w, 64, ci2c_b, U3, (long)NPIX * 64, 64, 32);
    // 14. g = t * ci1 * ci2
    g_eltwise_kernel<<<1024, 256, 0, stream>>>(T, CI1V, U3, G);
    // 15. channel_map = g @ cp_out^T  (K=64)
    gemm_nt128_kernel<<<8 * 32 * 3, 256, 0, stream>>>(
        G, (long)NPIX * 64, 64, cp_out_w, 64, cp_out_b, CMAP, (long)NPIX * 384, 384, 32);
    // 16. cm
    mean_kernel<<<dim3(6, 8), 256, 0, stream>>>(CMAP, CMv, 384);
    // 17. sp = conv_x @ sp_in^T  (M=192)
    gemm_nt64_kernel<<<8 * 32 * 3, 256, 0, stream>>>(
        CONVX, (long)NPIX * 384, 384, sp_in_w, 384, sp_in_b, SP, (long)NPIX * 192, 192, 32);
    // 18. d = dw3x3(sp)
    dw3_kernel<192><<<3072, 256, 0, stream>>>(SP, sp_dw_w, sp_dw_b, DDb);
    // 19. g2 = gelu(x1)*x2
    gelu_mul_kernel<<<1536, 256, 0, stream>>>(DDb, G2);
    // 20. spatial_map = g2 @ sp_out^T  (K=96)
    gemm_nt128_kernel<<<8 * 32 * 3, 256, 0, stream>>>(
        G2, (long)NPIX * 96, 96, sp_out_w, 96, sp_out_b, SMAP, (long)NPIX * 384, 384, 32);
    // 21. final mix (in-place on AT)
    final_mix_kernel<<<6144, 256, 0, stream>>>(AT, CMAP, SMAP, CONVX, CMv);
    // 22. prj = at @ proj_w^T
    gemm_nt128_kernel<<<8 * 32 * 3, 256, 0, stream>>>(
        AT, (long)NPIX * 384, 384, proj_w, 384, proj_b, PRJ, (long)NPIX * 384, 384, 32);
    // 23. out (B, 384, 4096) f32
    xpose_out_kernel<<<dim3(64, 6, 8), 256, 0, stream>>>(PRJ, (float*)d_out);
}

// Round 7
// 606.270 us; speedup vs baseline: 2.3126x; 2.3126x over previous
//
#include <hip/hip_runtime.h>
#include <hip/hip_bf16.h>

typedef __bf16 bf16;
typedef __bf16 bf16x4 __attribute__((ext_vector_type(4)));
typedef __bf16 bf16x8 __attribute__((ext_vector_type(8)));
typedef float f32x4 __attribute__((ext_vector_type(4)));

#define NPIX 4096

#if defined(__has_builtin)
#if __has_builtin(__builtin_amdgcn_global_load_lds)
#define HAS_GLL 1
#endif
#endif

// stage 16B per lane into LDS. GLL path: base must be WAVE-UNIFORM; HW scatters
// to base + lane*16. Fallback: per-lane store at base + lane*8 elems.
__device__ __forceinline__ void stage16(const bf16* __restrict__ g, bf16* base, int lane)
{
#ifdef HAS_GLL
    __builtin_amdgcn_global_load_lds(
        (const __attribute__((address_space(1))) void*)g,
        (__attribute__((address_space(3))) void*)base, 16, 0, 0);
#else
    *(bf16x8*)(base + lane * 8) = *(const bf16x8*)g;
#endif
}

// ---------------------------------------------------------------------------
// f32 -> bf16 conversion of the 8 GEMM weight tensors.
// ---------------------------------------------------------------------------
struct CvtArgs {
    const float* src[8];
    bf16* dst[8];
    long gpre[9];
};

__global__ __launch_bounds__(256) void cvt_kernel(CvtArgs a, long totalGroups)
{
    long g = (long)blockIdx.x * 256 + threadIdx.x;
    if (g >= totalGroups) return;
    int lo = 0, hi = 7;
    while (lo < hi) { int mid = (lo + hi) >> 1; if (g >= a.gpre[mid + 1]) lo = mid + 1; else hi = mid; }
    long off = (g - a.gpre[lo]) << 3;
    const float* s = a.src[lo] + off;
    float4 v0 = *(const float4*)s;
    float4 v1 = *(const float4*)(s + 4);
    bf16x8 o;
    o[0] = (bf16)v0.x; o[1] = (bf16)v0.y; o[2] = (bf16)v0.z; o[3] = (bf16)v0.w;
    o[4] = (bf16)v1.x; o[5] = (bf16)v1.y; o[6] = (bf16)v1.z; o[7] = (bf16)v1.w;
    *(bf16x8*)(a.dst[lo] + off) = o;
}

// ---------------------------------------------------------------------------
// x (B, 384, 4096) f32  ->  XT (B, 4096, 384) bf16.
// ---------------------------------------------------------------------------
__global__ __launch_bounds__(256) void xpose_in_kernel(
    const float* __restrict__ x, bf16* __restrict__ XT)
{
    __shared__ bf16 Lt[64][72];
    const int n0 = blockIdx.x << 6, c0 = blockIdx.y << 6, b = blockIdx.z;
    const int t = threadIdx.x;
    const int rr = t >> 4, q4 = (t & 15) << 2;
    #pragma unroll
    for (int it = 0; it < 4; it++) {
        int ci = rr + it * 16;
        float4 v = *(const float4*)(x + ((long)(b * 384 + c0 + ci) << 12) + n0 + q4);
        Lt[ci][q4 + 0] = (bf16)v.x; Lt[ci][q4 + 1] = (bf16)v.y;
        Lt[ci][q4 + 2] = (bf16)v.z; Lt[ci][q4 + 3] = (bf16)v.w;
    }
    __syncthreads();
    #pragma unroll
    for (int it = 0; it < 4; it++) {
        int ni = rr + it * 16;
        bf16x4 o;
        #pragma unroll
        for (int e = 0; e < 4; e++) o[e] = Lt[q4 + e][ni];
        *(bf16x4*)(XT + ((long)(b * NPIX + n0 + ni)) * 384 + c0 + q4) = o;
    }
}

// PRJ (B, 4096, 384) bf16 -> d_out (B, 384, 4096) f32.
__global__ __launch_bounds__(256) void xpose_out_kernel(
    const bf16* __restrict__ PRJ, float* __restrict__ outp)
{
    __shared__ bf16 Lt[64][72];
    const int n0 = blockIdx.x << 6, c0 = blockIdx.y << 6, b = blockIdx.z;
    const int t = threadIdx.x;
    const int rr = t >> 4, q4 = (t & 15) << 2;
    #pragma unroll
    for (int it = 0; it < 4; it++) {
        int ni = rr + it * 16;
        bf16x4 v = *(const bf16x4*)(PRJ + ((long)(b * NPIX + n0 + ni)) * 384 + c0 + q4);
        #pragma unroll
        for (int e = 0; e < 4; e++) Lt[ni][q4 + e] = v[e];
    }
    __syncthreads();
    #pragma unroll
    for (int it = 0; it < 4; it++) {
        int ci = rr + it * 16;
        float4 f;
        f.x = (float)Lt[q4 + 0][ci]; f.y = (float)Lt[q4 + 1][ci];
        f.z = (float)Lt[q4 + 2][ci]; f.w = (float)Lt[q4 + 3][ci];
        *(float4*)(outp + ((long)(b * 384 + c0 + ci) << 12) + n0 + q4) = f;
    }
}

// QKVT cols [0,768) (q,k) NHWC -> QKT (B, 768, 4096) NCHW bf16.
__global__ __launch_bounds__(256) void qk_xpose_kernel(
    const bf16* __restrict__ qkvt, bf16* __restrict__ qkt)
{
    __shared__ bf16 Lt[64][72];
    const int n0 = blockIdx.x << 6, c0 = blockIdx.y << 6, b = blockIdx.z;
    const int t = threadIdx.x;
    const int rr = t >> 4, q4 = (t & 15) << 2;
    #pragma unroll
    for (int it = 0; it < 4; it++) {
        int ni = rr + it * 16;
        bf16x4 v = *(const bf16x4*)(qkvt + ((long)(b * NPIX + n0 + ni)) * 1152 + c0 + q4);
        #pragma unroll
        for (int e = 0; e < 4; e++) Lt[ni][q4 + e] = v[e];
    }
    __syncthreads();
    #pragma unroll
    for (int it = 0; it < 4; it++) {
        int ci = rr + it * 16;
        bf16x4 o;
        #pragma unroll
        for (int e = 0; e < 4; e++) o[e] = Lt[q4 + e][ci];
        *(bf16x4*)(qkt + ((long)(b * 768 + c0 + ci) << 12) + n0 + q4) = o;
    }
}

// ---------------------------------------------------------------------------
// m97-style BT-GEMM, 128n x 128m, BK=32: O[b][n][m] = A[n][:].W[m][:] + bias.
// Both operands k-contiguous; LDS [128][32] unpadded; global_load_lds w=16.
// ---------------------------------------------------------------------------
__global__ __launch_bounds__(256) void gemm_bt128_kernel(
    const bf16* __restrict__ Xg, long xBatch, int xRow,
    const bf16* __restrict__ Wg, int K,
    const float* __restrict__ bias, bf16* __restrict__ Og,
    long oBatch, int oRow, int nTiles)
{
    __shared__ bf16 At[128 * 32];
    __shared__ bf16 Bt[128 * 32];
    const int t = threadIdx.x;
    const int lin = blockIdx.x;
    const int b = lin & 7;
    const int rest = lin >> 3;
    const int nBase = (rest % nTiles) << 7;
    const int mBase = (rest / nTiles) << 7;
    const int lane = t & 63, wv = t >> 6;
    const int nOff = (wv & 1) << 6, mOff = (wv >> 1) << 6;
    const int lr = lane & 15, qd = lane >> 4;
    const int srow = t >> 2, skb = (t & 3) << 3;
    const bf16* Ap0 = Xg + (long)b * xBatch + (long)(nBase + srow) * xRow + skb;
    const bf16* Ap1 = Ap0 + (long)64 * xRow;
    const bf16* Bp0 = Wg + (long)(mBase + srow) * K + skb;
    const bf16* Bp1 = Bp0 + (long)64 * K;
    bf16* Aw = At + wv * 512;        // wave-uniform stage base (elements)
    bf16* Bw = Bt + wv * 512;

    f32x4 acc[4][4] = {};
    for (int k0 = 0; k0 < K; k0 += 32) {
        __syncthreads();                       // prev iter's ds_reads done
        stage16(Ap0 + k0, Aw, lane);
        stage16(Ap1 + k0, Aw + 2048, lane);
        stage16(Bp0 + k0, Bw, lane);
        stage16(Bp1 + k0, Bw + 2048, lane);
        __syncthreads();                       // vmcnt drain + visibility
        bf16x8 a[4], bb[4];
        #pragma unroll
        for (int i = 0; i < 4; i++) {
            a[i]  = *(const bf16x8*)(At + (nOff + i * 16 + lr) * 32 + qd * 8);
            bb[i] = *(const bf16x8*)(Bt + (mOff + i * 16 + lr) * 32 + qd * 8);
        }
        #pragma unroll
        for (int i = 0; i < 4; i++)
            #pragma unroll
            for (int j = 0; j < 4; j++)
                acc[i][j] = __builtin_amdgcn_mfma_f32_16x16x32_bf16(a[i], bb[j], acc[i][j], 0, 0, 0);
    }

    float bj[4];
    #pragma unroll
    for (int j = 0; j < 4; j++) bj[j] = bias ? bias[mBase + mOff + j * 16 + lr] : 0.f;
    bf16* Ob = Og + (long)b * oBatch;
    #pragma unroll
    for (int i = 0; i < 4; i++)
        #pragma unroll
        for (int r = 0; r < 4; r++) {
            long rowOff = (long)(nBase + nOff + i * 16 + qd * 4 + r) * oRow;
            #pragma unroll
            for (int j = 0; j < 4; j++)
                Ob[rowOff + mBase + mOff + j * 16 + lr] = (bf16)(acc[i][j][r] + bj[j]);
        }
}

// ---------------------------------------------------------------------------
// BT-GEMM, 128n x 64m (M % 64 == 0). A-tile 128x32, B-tile 64x32.
// ---------------------------------------------------------------------------
__global__ __launch_bounds__(256) void gemm_bt64_kernel(
    const bf16* __restrict__ Xg, long xBatch, int xRow,
    const bf16* __restrict__ Wg, int K,
    const float* __restrict__ bias, bf16* __restrict__ Og,
    long oBatch, int oRow, int nTiles)
{
    __shared__ bf16 At[128 * 32];
    __shared__ bf16 Bt[64 * 32];
    const int t = threadIdx.x;
    const int lin = blockIdx.x;
    const int b = lin & 7;
    const int rest = lin >> 3;
    const int nBase = (rest % nTiles) << 7;
    const int mBase = (rest / nTiles) << 6;
    const int lane = t & 63, wv = t >> 6;
    const int nOff = wv << 5;
    const int lr = lane & 15, qd = lane >> 4;
    const int srow = t >> 2, skb = (t & 3) << 3;
    const bf16* Ap0 = Xg + (long)b * xBatch + (long)(nBase + srow) * xRow + skb;
    const bf16* Ap1 = Ap0 + (long)64 * xRow;
    const bf16* Bp0 = Wg + (long)(mBase + srow) * K + skb;
    bf16* Aw = At + wv * 512;
    bf16* Bw = Bt + wv * 512;

    f32x4 acc[2][4] = {};
    for (int k0 = 0; k0 < K; k0 += 32) {
        __syncthreads();
        stage16(Ap0 + k0, Aw, lane);
        stage16(Ap1 + k0, Aw + 2048, lane);
        stage16(Bp0 + k0, Bw, lane);
        __syncthreads();
        bf16x8 a[2], bb[4];
        #pragma unroll
        for (int i = 0; i < 2; i++)
            a[i] = *(const bf16x8*)(At + (nOff + i * 16 + lr) * 32 + qd * 8);
        #pragma unroll
        for (int j = 0; j < 4; j++)
            bb[j] = *(const bf16x8*)(Bt + (j * 16 + lr) * 32 + qd * 8);
        #pragma unroll
        for (int i = 0; i < 2; i++)
            #pragma unroll
            for (int j = 0; j < 4; j++)
                acc[i][j] = __builtin_amdgcn_mfma_f32_16x16x32_bf16(a[i], bb[j], acc[i][j], 0, 0, 0);
    }

    float bj[4];
    #pragma unroll
    for (int j = 0; j < 4; j++) bj[j] = bias ? bias[mBase + j * 16 + lr] : 0.f;
    bf16* Ob = Og + (long)b * oBatch;
    #pragma unroll
    for (int i = 0; i < 2; i++)
        #pragma unroll
        for (int r = 0; r < 4; r++) {
            long rowOff = (long)(nBase + nOff + i * 16 + qd * 4 + r) * oRow;
            #pragma unroll
            for (int j = 0; j < 4; j++)
                Ob[rowOff + mBase + j * 16 + lr] = (bf16)(acc[i][j][r] + bj[j]);
        }
}

// ---------------------------------------------------------------------------
// Row inverse L2 norms over QKT (contiguous rows). grid (768, B).
// ---------------------------------------------------------------------------
__global__ __launch_bounds__(256) void rownorm_kernel(
    const bf16* __restrict__ qkt, float* __restrict__ invn)
{
    const int c = blockIdx.x, b = blockIdx.y;
    const bf16* p = qkt + ((long)b * 768 + c) * NPIX;
    float s = 0.f;
    for (int i = threadIdx.x * 8; i < NPIX; i += 2048) {
        bf16x8 v = *(const bf16x8*)(p + i);
        #pragma unroll
        for (int e = 0; e < 8; e++) { float f = (float)v[e]; s += f * f; }
    }
    #pragma unroll
    for (int o = 32; o; o >>= 1) s += __shfl_down(s, o, 64);
    __shared__ float red[4];
    if ((threadIdx.x & 63) == 0) red[threadIdx.x >> 6] = s;
    __syncthreads();
    if (threadIdx.x == 0) {
        float tot = red[0] + red[1] + red[2] + red[3];
        invn[b * 768 + c] = 1.0f / fmaxf(sqrtf(tot), 1e-12f);
    }
}

// ---------------------------------------------------------------------------
// Attention logits partials from QKT (direct-from-global, k=n contiguous).
// grid (8, 64); slot = kc*4 + wave covers 128 n.
// ---------------------------------------------------------------------------
__global__ __launch_bounds__(256) void attn_logits_kernel(
    const bf16* __restrict__ qkt, float* __restrict__ part)
{
    const int kc = blockIdx.x;
    const int bh = blockIdx.y;
    const int b = bh >> 3, h = bh & 7;
    const int t = threadIdx.x, lane = t & 63, wv = t >> 6;
    const int lr = lane & 15, qd = lane >> 4;
    const bf16* qb = qkt + (long)b * 768 * NPIX + (long)h * 48 * NPIX;
    const bf16* kb = qb + (long)384 * NPIX;
    const int k0b = (kc * 4 + wv) * 128;
    f32x4 acc[3][3] = {};
    for (int s = 0; s < 4; s++) {
        const int k0 = k0b + s * 32;
        bf16x8 a[3], bb[3];
        #pragma unroll
        for (int i = 0; i < 3; i++) {
            a[i]  = *(const bf16x8*)(qb + (long)(i * 16 + lr) * NPIX + k0 + qd * 8);
            bb[i] = *(const bf16x8*)(kb + (long)(i * 16 + lr) * NPIX + k0 + qd * 8);
        }
        #pragma unroll
        for (int i = 0; i < 3; i++)
            #pragma unroll
            for (int j = 0; j < 3; j++)
                acc[i][j] = __builtin_amdgcn_mfma_f32_16x16x32_bf16(a[i], bb[j], acc[i][j], 0, 0, 0);
    }
    float* pp = part + ((long)bh * 32 + kc * 4 + wv) * 2304;
    #pragma unroll
    for (int i = 0; i < 3; i++)
        #pragma unroll
        for (int j = 0; j < 3; j++)
            #pragma unroll
            for (int r = 0; r < 4; r++)
                pp[(i * 16 + qd * 4 + r) * 48 + j * 16 + lr] = acc[i][j][r];
}

// Sum 32 partial slots, scale, softmax.
__global__ __launch_bounds__(256) void attn_softmax_kernel(
    const float* __restrict__ part, const float* __restrict__ invn,
    const float* __restrict__ temp, float* __restrict__ attn)
{
    __shared__ float sl[2304];
    const int bh = blockIdx.x, b = bh >> 3, h = bh & 7;
    const int t = threadIdx.x;
    const float tmp = temp[h];
    for (int idx = t; idx < 2304; idx += 256) {
        float s = 0.f;
        for (int p = 0; p < 32; p++) s += part[((long)bh * 32 + p) * 2304 + idx];
        int d = idx / 48, e = idx - d * 48;
        s *= invn[b * 768 + h * 48 + d] * invn[b * 768 + 384 + h * 48 + e] * tmp;
        sl[idx] = s;
    }
    __syncthreads();
    if (t < 48) {
        float m = -1e30f;
        #pragma unroll
        for (int e = 0; e < 48; e++) m = fmaxf(m, sl[t * 48 + e]);
        float ex[48]; float sum = 0.f;
        #pragma unroll
        for (int e = 0; e < 48; e++) { ex[e] = expf(sl[t * 48 + e] - m); sum += ex[e]; }
        float inv = 1.0f / sum;
        #pragma unroll
        for (int e = 0; e < 48; e++) attn[(long)bh * 2304 + t * 48 + e] = ex[e] * inv;
    }
}

// at[n][h*48+d] = sum_e attn[d][e] * v[n][e]  (NHWC, b128 in/out). grid (16,64).
__global__ __launch_bounds__(256) void attn_apply_kernel(
    const float* __restrict__ attn, const bf16* __restrict__ qkvt,
    bf16* __restrict__ at)
{
    __shared__ float sa[2304];
    const int bh = blockIdx.y, b = bh >> 3, h = bh & 7;
    const int t = threadIdx.x;
    for (int i = t; i < 2304; i += 256) sa[i] = attn[(long)bh * 2304 + i];
    __syncthreads();
    const int n = blockIdx.x * 256 + t;
    const bf16* vp = qkvt + ((long)(b * NPIX + n)) * 1152 + 768 + h * 48;
    float vv[48];
    #pragma unroll
    for (int cg = 0; cg < 6; cg++) {
        bf16x8 v = *(const bf16x8*)(vp + cg * 8);
        #pragma unroll
        for (int e = 0; e < 8; e++) vv[cg * 8 + e] = (float)v[e];
    }
    bf16* ap = at + ((long)(b * NPIX + n)) * 384 + h * 48;
    #pragma unroll
    for (int cg = 0; cg < 6; cg++) {
        bf16x8 o;
        #pragma unroll
        for (int dd = 0; dd < 8; dd++) {
            int d = cg * 8 + dd;
            float acc = 0.f;
            for (int e = 0; e < 48; e++) acc += sa[d * 48 + e] * vv[e];
            o[dd] = (bf16)acc;
        }
        *(bf16x8*)(ap + cg * 8) = o;
    }
}

// ---------------------------------------------------------------------------
// Depthwise 3x3, pad 1, NHWC.
// ---------------------------------------------------------------------------
template<int CH>
__global__ __launch_bounds__(256) void dw3_kernel(
    const bf16* __restrict__ in, const float* __restrict__ wt,
    const float* __restrict__ bias, bf16* __restrict__ outp)
{
    constexpr int G = CH / 8;
    const int gid = blockIdx.x * 256 + threadIdx.x;
    const int p = gid / G, cg = gid - p * G;
    const int b = p >> 12, pix = p & 4095, y = pix >> 6, xx = pix & 63;

    float wr[9][8];
    #pragma unroll
    for (int e = 0; e < 8; e++)
        #pragma unroll
        for (int tp = 0; tp < 9; tp++)
            wr[tp][e] = wt[(cg * 8 + e) * 9 + tp];

    float acc[8];
    #pragma unroll
    for (int e = 0; e < 8; e++) acc[e] = bias[cg * 8 + e];

    const bf16* ib = in + ((long)b << 12) * CH;
    #pragma unroll
    for (int dy = -1; dy <= 1; dy++) {
        int yy = y + dy;
        if (yy < 0 || yy >= 64) continue;
        #pragma unroll
        for (int dx = -1; dx <= 1; dx++) {
            int x2 = xx + dx;
            if (x2 < 0 || x2 >= 64) continue;
            bf16x8 v = *(const bf16x8*)(ib + (long)(yy * 64 + x2) * CH + cg * 8);
            int tp = (dy + 1) * 3 + (dx + 1);
            #pragma unroll
            for (int e = 0; e < 8; e++) acc[e] += wr[tp][e] * (float)v[e];
        }
    }
    bf16x8 o;
    #pragma unroll
    for (int e = 0; e < 8; e++) o[e] = (bf16)acc[e];
    *(bf16x8*)(outp + (long)p * CH + cg * 8) = o;
}

// Depthwise 7x7, dil 3, pad 9, CH=64, NHWC, weights in LDS.
__global__ __launch_bounds__(256) void dw7_kernel(
    const bf16* __restrict__ in, const float* __restrict__ wt,
    const float* __restrict__ bias, bf16* __restrict__ outp)
{
    __shared__ float wf[64 * 49];
    __shared__ float bfv[64];
    for (int i = threadIdx.x; i < 64 * 49; i += 256) wf[i] = wt[i];
    if (threadIdx.x < 64) bfv[threadIdx.x] = bias[threadIdx.x];
    __syncthreads();

    const int gid = blockIdx.x * 256 + threadIdx.x;
    const int cg = gid & 7, p = gid >> 3;
    const int b = p >> 12, pix = p & 4095, y = pix >> 6, xx = pix & 63;

    float acc[8];
    #pragma unroll
    for (int e = 0; e < 8; e++) acc[e] = bfv[cg * 8 + e];

    const bf16* ib = in + ((long)b << 12) * 64;
    for (int i = 0; i < 7; i++) {
        int yy = y + i * 3 - 9;
        if (yy < 0 || yy >= 64) continue;
        for (int j = 0; j < 7; j++) {
            int x2 = xx + j * 3 - 9;
            if (x2 < 0 || x2 >= 64) continue;
            bf16x8 v = *(const bf16x8*)(ib + (long)(yy * 64 + x2) * 64 + cg * 8);
            int tp = i * 7 + j;
            #pragma unroll
            for (int e = 0; e < 8; e++) acc[e] += wf[(cg * 8 + e) * 49 + tp] * (float)v[e];
        }
    }
    bf16x8 o;
    #pragma unroll
    for (int e = 0; e < 8; e++) o[e] = (bf16)acc[e];
    *(bf16x8*)(outp + (long)p * 64 + cg * 8) = o;
}

// ---------------------------------------------------------------------------
// Two-phase column mean over NHWC. Phase 1: grid (32, CH/64, B), 128 rows/blk.
// ---------------------------------------------------------------------------
__global__ __launch_bounds__(256) void colmean1_kernel(
    const bf16* __restrict__ in, float* __restrict__ partial, int CH)
{
    const int chunk = blockIdx.x, cb = blockIdx.y, b = blockIdx.z;
    const int c = (cb << 6) + (threadIdx.x & 63);
    const int rl = threadIdx.x >> 6;
    const bf16* base = in + ((long)b * NPIX + chunk * 128) * CH + c;
    float s = 0.f;
    for (int n = rl; n < 128; n += 4) s += (float)base[(long)n * CH];
    __shared__ float red[256];
    red[threadIdx.x] = s;
    __syncthreads();
    if (threadIdx.x < 64)
        partial[((long)(b * 32 + chunk)) * CH + (cb << 6) + threadIdx.x] =
            red[threadIdx.x] + red[threadIdx.x + 64] + red[threadIdx.x + 128] + red[threadIdx.x + 192];
}

__global__ __launch_bounds__(256) void colmean2_kernel(
    const float* __restrict__ partial, float* __restrict__ outp, int CH)
{
    int idx = blockIdx.x * 256 + threadIdx.x;
    if (idx >= 8 * CH) return;
    int b = idx / CH, c = idx - b * CH;
    float s = 0.f;
    for (int ch = 0; ch < 32; ch++) s += partial[((long)(b * 32 + ch)) * CH + c];
    outp[idx] = s * (1.0f / NPIX);
}

// ci1[b][o] = bias[o] + sum_i w[o][i]*tmean[b][i]
__global__ __launch_bounds__(64) void ci1_kernel(
    const float* __restrict__ tmean, const float* __restrict__ wt,
    const float* __restrict__ bias, float* __restrict__ ci1v)
{
    const int b = blockIdx.x, o = threadIdx.x;
    float s = bias[o];
    for (int i = 0; i < 64; i++) s += wt[o * 64 + i] * tmean[b * 64 + i];
    ci1v[b * 64 + o] = s;
}

// g[n][c] = t[n][c] * ci1[b][c] * u3[n][c]   (NHWC, CH=64)
__global__ __launch_bounds__(256) void g_eltwise_kernel(
    const bf16* __restrict__ t, const float* __restrict__ ci1v,
    const bf16* __restrict__ u3, bf16* __restrict__ g)
{
    unsigned idx = ((unsigned)blockIdx.x * 256 + threadIdx.x) << 3;
    unsigned row = idx >> 6, c0 = idx & 63;
    const float* cp = ci1v + (row >> 12) * 64 + c0;
    float4 s0 = *(const float4*)cp;
    float4 s1 = *(const float4*)(cp + 4);
    float sv[8] = {s0.x, s0.y, s0.z, s0.w, s1.x, s1.y, s1.z, s1.w};
    bf16x8 tv = *(const bf16x8*)(t + idx);
    bf16x8 uv = *(const bf16x8*)(u3 + idx);
    bf16x8 ov;
    #pragma unroll
    for (int e = 0; e < 8; e++) ov[e] = (bf16)((float)tv[e] * sv[e] * (float)uv[e]);
    *(bf16x8*)(g + idx) = ov;
}

// g2[n][c] = gelu_exact(d[n][c]) * d[n][c+96]
__global__ __launch_bounds__(256) void gelu_mul_kernel(
    const bf16* __restrict__ dd, bf16* __restrict__ g2)
{
    unsigned idx = ((unsigned)blockIdx.x * 256 + threadIdx.x) << 3;
    unsigned row = idx / 96, off = idx - row * 96;
    bf16x8 v1 = *(const bf16x8*)(dd + (long)row * 192 + off);
    bf16x8 v2 = *(const bf16x8*)(dd + (long)row * 192 + off + 96);
    bf16x8 ov;
    #pragma unroll
    for (int e = 0; e < 8; e++) {
        float x1 = (float)v1[e];
        float g = 0.5f * x1 * (1.0f + erff(x1 * 0.70710678118654752f));
        ov[e] = (bf16)(g * (float)v2[e]);
    }
    *(bf16x8*)(g2 + idx) = ov;
}

// at = (at + cmap)*sigmoid(smap) + convx*sigmoid(cm[b][c])
__global__ __launch_bounds__(256) void final_mix_kernel(
    bf16* __restrict__ at, const bf16* __restrict__ cmap,
    const bf16* __restrict__ smap, const bf16* __restrict__ convx,
    const float* __restrict__ cm)
{
    unsigned idx = ((unsigned)blockIdx.x * 256 + threadIdx.x) << 3;
    unsigned row = idx / 384, c0 = idx - row * 384;
    const float* cp = cm + (row >> 12) * 384 + c0;
    float4 s0 = *(const float4*)cp;
    float4 s1 = *(const float4*)(cp + 4);
    float gv[8] = {s0.x, s0.y, s0.z, s0.w, s1.x, s1.y, s1.z, s1.w};
    bf16x8 av = *(const bf16x8*)(at + idx);
    bf16x8 cv = *(const bf16x8*)(cmap + idx);
    bf16x8 sv = *(const bf16x8*)(smap + idx);
    bf16x8 xv = *(const bf16x8*)(convx + idx);
    bf16x8 ov;
    #pragma unroll
    for (int e = 0; e < 8; e++) {
        float a = (float)av[e] + (float)cv[e];
        float s = 1.0f / (1.0f + expf(-(float)sv[e]));
        float g = 1.0f / (1.0f + expf(-gv[e]));
        ov[e] = (bf16)(a * s + (float)xv[e] * g);
    }
    *(bf16x8*)(at + idx) = ov;
}

// ---------------------------------------------------------------------------
extern "C" void kernel_launch(void* const* d_in, const int* in_sizes, int n_in,
                              void* d_out, int out_size, void* d_ws, size_t ws_size,
                              hipStream_t stream)
{
    const int B = 8;
    const long NB = (long)B * NPIX;

    char* wsp = (char*)d_ws;
    size_t off = 0;
    auto alloc = [&](size_t bytes) -> char* {
        char* p = wsp + off; off += (bytes + 255) & ~(size_t)255; return p;
    };

    const int cvtIdx[8] = {2, 3, 5, 9, 17, 19, 21, 25};
    bf16* wcv[8];
    CvtArgs ca;
    long gpre = 0;
    for (int i = 0; i < 8; i++) {
        int ti = cvtIdx[i];
        wcv[i] = (bf16*)alloc((size_t)in_sizes[ti] * 2);
        ca.src[i] = (const float*)d_in[ti];
        ca.dst[i] = wcv[i];
        ca.gpre[i] = gpre;
        gpre += in_sizes[ti] >> 3;
    }
    ca.gpre[8] = gpre;

    const bf16 *qkv_w = wcv[0], *proj_w = wcv[1], *dw1_w = wcv[2], *cp_in_w = wcv[3],
               *ci2c_w = wcv[4], *cp_out_w = wcv[5], *sp_in_w = wcv[6], *sp_out_w = wcv[7];

    const float* xf      = (const float*)d_in[0];
    const float* temp    = (const float*)d_in[1];
    const float* proj_b  = (const float*)d_in[4];
    const float* dw1_b   = (const float*)d_in[6];
    const float* dw2_w   = (const float*)d_in[7];
    const float* dw2_b   = (const float*)d_in[8];
    const float* cp_in_b = (const float*)d_in[10];
    const float* ci1_w   = (const float*)d_in[11];
    const float* ci1_b   = (const float*)d_in[12];
    const float* ci2a_w  = (const float*)d_in[13];
    const float* ci2a_b  = (const float*)d_in[14];
    const float* ci2b_w  = (const float*)d_in[15];
    const float* ci2b_b  = (const float*)d_in[16];
    const float* ci2c_b  = (const float*)d_in[18];
    const float* cp_out_b= (const float*)d_in[20];
    const float* sp_in_b = (const float*)d_in[22];
    const float* sp_dw_w = (const float*)d_in[23];
    const float* sp_dw_b = (const float*)d_in[24];
    const float* sp_out_b= (const float*)d_in[26];

    bf16*  XT    = (bf16*) alloc(NB * 384 * 2);
    bf16*  QKVT  = (bf16*) alloc(NB * 1152 * 2);
    bf16*  AT    = (bf16*) alloc(NB * 384 * 2);
    bf16*  CONV1 = (bf16*) alloc(NB * 384 * 2);   // also first half of QKT
    bf16*  CONVX = (bf16*) alloc(NB * 384 * 2);   // also second half of QKT
    bf16*  CMAP  = (bf16*) alloc(NB * 384 * 2);
    bf16*  T     = (bf16*) alloc(NB * 64 * 2);
    bf16*  U1    = (bf16*) alloc(NB * 64 * 2);
    bf16*  U2    = (bf16*) alloc(NB * 64 * 2);
    bf16*  SP    = (bf16*) alloc(NB * 192 * 2);
    bf16*  DDb   = (bf16*) alloc(NB * 192 * 2);
    float* PART  = (float*)alloc((size_t)64 * 32 * 2304 * 4);
    float* ATTN  = (float*)alloc((size_t)64 * 2304 * 4);
    float* INVN  = (float*)alloc((size_t)B * 768 * 4);
    float* PARTM = (float*)alloc((size_t)B * 32 * 384 * 4);
    float* TMEAN = (float*)alloc((size_t)B * 64 * 4);
    float* CI1V  = (float*)alloc((size_t)B * 64 * 4);
    float* CMv   = (float*)alloc((size_t)B * 384 * 4);
    bf16* QKT  = CONV1;   // 50 MB: CONV1+CONVX contiguous; QKT dead before dw1
    bf16* SMAP = CONV1;   // CONV1 dead after dw3
    bf16* G2   = SP;      // SP dead after dw3<192>
    bf16* U3   = U1;      // U1 dead after dw7
    bf16* G    = U2;      // U2 dead after ci2c
    bf16* PRJ  = QKVT;    // QKVT dead after dw1

    // 0. weight cvt + x transpose
    cvt_kernel<<<(int)((gpre + 255) / 256), 256, 0, stream>>>(ca, gpre);
    xpose_in_kernel<<<dim3(64, 6, 8), 256, 0, stream>>>(xf, XT);

    // 1. QKVT = XT @ qkv_w^T   (B, 4096, 1152)
    gemm_bt128_kernel<<<8 * 32 * 9, 256, 0, stream>>>(
        XT, (long)NPIX * 384, 384, qkv_w, 384, nullptr, QKVT, (long)NPIX * 1152, 1152, 32);
    // 2. q,k -> NCHW copy; row norms
    qk_xpose_kernel<<<dim3(64, 12, 8), 256, 0, stream>>>(QKVT, QKT);
    rownorm_kernel<<<dim3(768, 8), 256, 0, stream>>>(QKT, INVN);
    // 3-5. attention
    attn_logits_kernel<<<dim3(8, 64), 256, 0, stream>>>(QKT, PART);
    attn_softmax_kernel<<<64, 256, 0, stream>>>(PART, INVN, temp, ATTN);
    attn_apply_kernel<<<dim3(16, 64), 256, 0, stream>>>(ATTN, QKVT, AT);
    // 6. conv1 = v @ dw1^T  (overwrites QKT low half — QKT dead)
    gemm_bt128_kernel<<<8 * 32 * 3, 256, 0, stream>>>(
        QKVT + 768, (long)NPIX * 1152, 1152, dw1_w, 384, dw1_b, CONV1, (long)NPIX * 384, 384, 32);
    // 7. conv_x = dw3x3(conv1)
    dw3_kernel<384><<<6144, 256, 0, stream>>>(CONV1, dw2_w, dw2_b, CONVX);
    // 8. t = at @ cp_in^T (M=64)
    gemm_bt64_kernel<<<8 * 32, 256, 0, stream>>>(
        AT, (long)NPIX * 384, 384, cp_in_w, 384, cp_in_b, T, (long)NPIX * 64, 64, 32);
    // 9-10. ci1
    colmean1_kernel<<<dim3(32, 1, 8), 256, 0, stream>>>(T, PARTM, 64);
    colmean2_kernel<<<2, 256, 0, stream>>>(PARTM, TMEAN, 64);
    ci1_kernel<<<8, 64, 0, stream>>>(TMEAN, ci1_w, ci1_b, CI1V);
    // 11-13. ci2 chain
    dw3_kernel<64><<<1024, 256, 0, stream>>>(T, ci2a_w, ci2a_b, U1);
    dw7_kernel<<<1024, 256, 0, stream>>>(U1, ci2b_w, ci2b_b, U2);
    gemm_bt64_kernel<<<8 * 32, 256, 0, stream>>>(
        U2, (long)NPIX * 64, 64, ci2c_w, 64, ci2c_b, U3, (long)NPIX * 64, 64, 32);
    // 14. g = t * ci1 * ci2
    g_eltwise_kernel<<<1024, 256, 0, stream>>>(T, CI1V, U3, G);
    // 15. channel_map = g @ cp_out^T (K=64)
    gemm_bt128_kernel<<<8 * 32 * 3, 256, 0, stream>>>(
        G, (long)NPIX * 64, 64, cp_out_w, 64, cp_out_b, CMAP, (long)NPIX * 384, 384, 32);
    // 16. cm = colmean(CMAP)
    colmean1_kernel<<<dim3(32, 6, 8), 256, 0, stream>>>(CMAP, PARTM, 384);
    colmean2_kernel<<<12, 256, 0, stream>>>(PARTM, CMv, 384);
    // 17. sp = conv_x @ sp_in^T (M=192)
    gemm_bt64_kernel<<<8 * 32 * 3, 256, 0, stream>>>(
        CONVX, (long)NPIX * 384, 384, sp_in_w, 384, sp_in_b, SP, (long)NPIX * 192, 192, 32);
    // 18. d = dw3x3(sp)
    dw3_kernel<192><<<3072, 256, 0, stream>>>(SP, sp_dw_w, sp_dw_b, DDb);
    // 19. g2 = gelu(x1)*x2
    gelu_mul_kernel<<<1536, 256, 0, stream>>>(DDb, G2);
    // 20. spatial_map = g2 @ sp_out^T (K=96)
    gemm_bt128_kernel<<<8 * 32 * 3, 256, 0, stream>>>(
        G2, (long)NPIX * 96, 96, sp_out_w, 96, sp_out_b, SMAP, (long)NPIX * 384, 384, 32);
    // 21. final mix (in-place on AT)
    final_mix_kernel<<<6144, 256, 0, stream>>>(AT, CMAP, SMAP, CONVX, CMv);
    // 22. prj = at @ proj_w^T
    gemm_bt128_kernel<<<8 * 32 * 3, 256, 0, stream>>>(
        AT, (long)NPIX * 384, 384, proj_w, 384, proj_b, PRJ, (long)NPIX * 384, 384, 32);
    // 23. out (B, 384, 4096) f32
    xpose_out_kernel<<<dim3(64, 6, 8), 256, 0, stream>>>(PRJ, (float*)d_out);
}

// Round 8
// 559.669 us; speedup vs baseline: 2.5051x; 1.0833x over previous
//
#include <hip/hip_runtime.h>
#include <hip/hip_bf16.h>

typedef __bf16 bf16;
typedef __bf16 bf16x4 __attribute__((ext_vector_type(4)));
typedef __bf16 bf16x8 __attribute__((ext_vector_type(8)));
typedef float f32x4 __attribute__((ext_vector_type(4)));

#define NPIX 4096

#if defined(__has_builtin)
#if __has_builtin(__builtin_amdgcn_global_load_lds)
#define HAS_GLL 1
#endif
#endif

// stage 16B per lane into LDS. GLL path: base must be WAVE-UNIFORM; HW scatters
// to base + lane*16. Fallback: per-lane store at base + lane*8 elems.
__device__ __forceinline__ void stage16(const bf16* __restrict__ g, bf16* base, int lane)
{
#ifdef HAS_GLL
    __builtin_amdgcn_global_load_lds(
        (const __attribute__((address_space(1))) void*)g,
        (__attribute__((address_space(3))) void*)base, 16, 0, 0);
#else
    *(bf16x8*)(base + lane * 8) = *(const bf16x8*)g;
#endif
}

// ---------------------------------------------------------------------------
// f32 -> bf16 conversion of the 8 GEMM weight tensors.
// ---------------------------------------------------------------------------
struct CvtArgs {
    const float* src[8];
    bf16* dst[8];
    long gpre[9];
};

__global__ __launch_bounds__(256) void cvt_kernel(CvtArgs a, long totalGroups)
{
    long g = (long)blockIdx.x * 256 + threadIdx.x;
    if (g >= totalGroups) return;
    int lo = 0, hi = 7;
    while (lo < hi) { int mid = (lo + hi) >> 1; if (g >= a.gpre[mid + 1]) lo = mid + 1; else hi = mid; }
    long off = (g - a.gpre[lo]) << 3;
    const float* s = a.src[lo] + off;
    float4 v0 = *(const float4*)s;
    float4 v1 = *(const float4*)(s + 4);
    bf16x8 o;
    o[0] = (bf16)v0.x; o[1] = (bf16)v0.y; o[2] = (bf16)v0.z; o[3] = (bf16)v0.w;
    o[4] = (bf16)v1.x; o[5] = (bf16)v1.y; o[6] = (bf16)v1.z; o[7] = (bf16)v1.w;
    *(bf16x8*)(a.dst[lo] + off) = o;
}

// ---------------------------------------------------------------------------
// x (B, 384, 4096) f32  ->  XT (B, 4096, 384) bf16.
// ---------------------------------------------------------------------------
__global__ __launch_bounds__(256) void xpose_in_kernel(
    const float* __restrict__ x, bf16* __restrict__ XT)
{
    __shared__ bf16 Lt[64][72];
    const int n0 = blockIdx.x << 6, c0 = blockIdx.y << 6, b = blockIdx.z;
    const int t = threadIdx.x;
    const int rr = t >> 4, q4 = (t & 15) << 2;
    #pragma unroll
    for (int it = 0; it < 4; it++) {
        int ci = rr + it * 16;
        float4 v = *(const float4*)(x + ((long)(b * 384 + c0 + ci) << 12) + n0 + q4);
        Lt[ci][q4 + 0] = (bf16)v.x; Lt[ci][q4 + 1] = (bf16)v.y;
        Lt[ci][q4 + 2] = (bf16)v.z; Lt[ci][q4 + 3] = (bf16)v.w;
    }
    __syncthreads();
    #pragma unroll
    for (int it = 0; it < 4; it++) {
        int ni = rr + it * 16;
        bf16x4 o;
        #pragma unroll
        for (int e = 0; e < 4; e++) o[e] = Lt[q4 + e][ni];
        *(bf16x4*)(XT + ((long)(b * NPIX + n0 + ni)) * 384 + c0 + q4) = o;
    }
}

// PRJ (B, 4096, 384) bf16 -> d_out (B, 384, 4096) f32.
__global__ __launch_bounds__(256) void xpose_out_kernel(
    const bf16* __restrict__ PRJ, float* __restrict__ outp)
{
    __shared__ bf16 Lt[64][72];
    const int n0 = blockIdx.x << 6, c0 = blockIdx.y << 6, b = blockIdx.z;
    const int t = threadIdx.x;
    const int rr = t >> 4, q4 = (t & 15) << 2;
    #pragma unroll
    for (int it = 0; it < 4; it++) {
        int ni = rr + it * 16;
        bf16x4 v = *(const bf16x4*)(PRJ + ((long)(b * NPIX + n0 + ni)) * 384 + c0 + q4);
        #pragma unroll
        for (int e = 0; e < 4; e++) Lt[ni][q4 + e] = v[e];
    }
    __syncthreads();
    #pragma unroll
    for (int it = 0; it < 4; it++) {
        int ci = rr + it * 16;
        float4 f;
        f.x = (float)Lt[q4 + 0][ci]; f.y = (float)Lt[q4 + 1][ci];
        f.z = (float)Lt[q4 + 2][ci]; f.w = (float)Lt[q4 + 3][ci];
        *(float4*)(outp + ((long)(b * 384 + c0 + ci) << 12) + n0 + q4) = f;
    }
}

// QKVT cols [0,768) (q,k) NHWC -> QKT (B, 768, 4096) NCHW bf16.
__global__ __launch_bounds__(256) void qk_xpose_kernel(
    const bf16* __restrict__ qkvt, bf16* __restrict__ qkt)
{
    __shared__ bf16 Lt[64][72];
    const int n0 = blockIdx.x << 6, c0 = blockIdx.y << 6, b = blockIdx.z;
    const int t = threadIdx.x;
    const int rr = t >> 4, q4 = (t & 15) << 2;
    #pragma unroll
    for (int it = 0; it < 4; it++) {
        int ni = rr + it * 16;
        bf16x4 v = *(const bf16x4*)(qkvt + ((long)(b * NPIX + n0 + ni)) * 1152 + c0 + q4);
        #pragma unroll
        for (int e = 0; e < 4; e++) Lt[ni][q4 + e] = v[e];
    }
    __syncthreads();
    #pragma unroll
    for (int it = 0; it < 4; it++) {
        int ci = rr + it * 16;
        bf16x4 o;
        #pragma unroll
        for (int e = 0; e < 4; e++) o[e] = Lt[q4 + e][ci];
        *(bf16x4*)(qkt + ((long)(b * 768 + c0 + ci) << 12) + n0 + q4) = o;
    }
}

// ---------------------------------------------------------------------------
// m97-style BT-GEMM, 128n x 128m, BK=32: O[b][n][m] = A[n][:].W[m][:] + bias.
// ---------------------------------------------------------------------------
__global__ __launch_bounds__(256) void gemm_bt128_kernel(
    const bf16* __restrict__ Xg, long xBatch, int xRow,
    const bf16* __restrict__ Wg, int K,
    const float* __restrict__ bias, bf16* __restrict__ Og,
    long oBatch, int oRow, int nTiles)
{
    __shared__ bf16 At[128 * 32];
    __shared__ bf16 Bt[128 * 32];
    const int t = threadIdx.x;
    const int lin = blockIdx.x;
    const int b = lin & 7;
    const int rest = lin >> 3;
    const int nBase = (rest % nTiles) << 7;
    const int mBase = (rest / nTiles) << 7;
    const int lane = t & 63, wv = t >> 6;
    const int nOff = (wv & 1) << 6, mOff = (wv >> 1) << 6;
    const int lr = lane & 15, qd = lane >> 4;
    const int srow = t >> 2, skb = (t & 3) << 3;
    const bf16* Ap0 = Xg + (long)b * xBatch + (long)(nBase + srow) * xRow + skb;
    const bf16* Ap1 = Ap0 + (long)64 * xRow;
    const bf16* Bp0 = Wg + (long)(mBase + srow) * K + skb;
    const bf16* Bp1 = Bp0 + (long)64 * K;
    bf16* Aw = At + wv * 512;
    bf16* Bw = Bt + wv * 512;

    f32x4 acc[4][4] = {};
    for (int k0 = 0; k0 < K; k0 += 32) {
        __syncthreads();
        stage16(Ap0 + k0, Aw, lane);
        stage16(Ap1 + k0, Aw + 2048, lane);
        stage16(Bp0 + k0, Bw, lane);
        stage16(Bp1 + k0, Bw + 2048, lane);
        __syncthreads();
        bf16x8 a[4], bb[4];
        #pragma unroll
        for (int i = 0; i < 4; i++) {
            a[i]  = *(const bf16x8*)(At + (nOff + i * 16 + lr) * 32 + qd * 8);
            bb[i] = *(const bf16x8*)(Bt + (mOff + i * 16 + lr) * 32 + qd * 8);
        }
        #pragma unroll
        for (int i = 0; i < 4; i++)
            #pragma unroll
            for (int j = 0; j < 4; j++)
                acc[i][j] = __builtin_amdgcn_mfma_f32_16x16x32_bf16(a[i], bb[j], acc[i][j], 0, 0, 0);
    }

    float bj[4];
    #pragma unroll
    for (int j = 0; j < 4; j++) bj[j] = bias ? bias[mBase + mOff + j * 16 + lr] : 0.f;
    bf16* Ob = Og + (long)b * oBatch;
    #pragma unroll
    for (int i = 0; i < 4; i++)
        #pragma unroll
        for (int r = 0; r < 4; r++) {
            long rowOff = (long)(nBase + nOff + i * 16 + qd * 4 + r) * oRow;
            #pragma unroll
            for (int j = 0; j < 4; j++)
                Ob[rowOff + mBase + mOff + j * 16 + lr] = (bf16)(acc[i][j][r] + bj[j]);
        }
}

// ---------------------------------------------------------------------------
// BT-GEMM, 128n x 64m (M % 64 == 0).
// ---------------------------------------------------------------------------
__global__ __launch_bounds__(256) void gemm_bt64_kernel(
    const bf16* __restrict__ Xg, long xBatch, int xRow,
    const bf16* __restrict__ Wg, int K,
    const float* __restrict__ bias, bf16* __restrict__ Og,
    long oBatch, int oRow, int nTiles)
{
    __shared__ bf16 At[128 * 32];
    __shared__ bf16 Bt[64 * 32];
    const int t = threadIdx.x;
    const int lin = blockIdx.x;
    const int b = lin & 7;
    const int rest = lin >> 3;
    const int nBase = (rest % nTiles) << 7;
    const int mBase = (rest / nTiles) << 6;
    const int lane = t & 63, wv = t >> 6;
    const int nOff = wv << 5;
    const int lr = lane & 15, qd = lane >> 4;
    const int srow = t >> 2, skb = (t & 3) << 3;
    const bf16* Ap0 = Xg + (long)b * xBatch + (long)(nBase + srow) * xRow + skb;
    const bf16* Ap1 = Ap0 + (long)64 * xRow;
    const bf16* Bp0 = Wg + (long)(mBase + srow) * K + skb;
    bf16* Aw = At + wv * 512;
    bf16* Bw = Bt + wv * 512;

    f32x4 acc[2][4] = {};
    for (int k0 = 0; k0 < K; k0 += 32) {
        __syncthreads();
        stage16(Ap0 + k0, Aw, lane);
        stage16(Ap1 + k0, Aw + 2048, lane);
        stage16(Bp0 + k0, Bw, lane);
        __syncthreads();
        bf16x8 a[2], bb[4];
        #pragma unroll
        for (int i = 0; i < 2; i++)
            a[i] = *(const bf16x8*)(At + (nOff + i * 16 + lr) * 32 + qd * 8);
        #pragma unroll
        for (int j = 0; j < 4; j++)
            bb[j] = *(const bf16x8*)(Bt + (j * 16 + lr) * 32 + qd * 8);
        #pragma unroll
        for (int i = 0; i < 2; i++)
            #pragma unroll
            for (int j = 0; j < 4; j++)
                acc[i][j] = __builtin_amdgcn_mfma_f32_16x16x32_bf16(a[i], bb[j], acc[i][j], 0, 0, 0);
    }

    float bj[4];
    #pragma unroll
    for (int j = 0; j < 4; j++) bj[j] = bias ? bias[mBase + j * 16 + lr] : 0.f;
    bf16* Ob = Og + (long)b * oBatch;
    #pragma unroll
    for (int i = 0; i < 2; i++)
        #pragma unroll
        for (int r = 0; r < 4; r++) {
            long rowOff = (long)(nBase + nOff + i * 16 + qd * 4 + r) * oRow;
            #pragma unroll
            for (int j = 0; j < 4; j++)
                Ob[rowOff + mBase + j * 16 + lr] = (bf16)(acc[i][j][r] + bj[j]);
        }
}

// ---------------------------------------------------------------------------
// Row inverse L2 norms over QKT (contiguous rows). grid (768, B).
// ---------------------------------------------------------------------------
__global__ __launch_bounds__(256) void rownorm_kernel(
    const bf16* __restrict__ qkt, float* __restrict__ invn)
{
    const int c = blockIdx.x, b = blockIdx.y;
    const bf16* p = qkt + ((long)b * 768 + c) * NPIX;
    float s = 0.f;
    for (int i = threadIdx.x * 8; i < NPIX; i += 2048) {
        bf16x8 v = *(const bf16x8*)(p + i);
        #pragma unroll
        for (int e = 0; e < 8; e++) { float f = (float)v[e]; s += f * f; }
    }
    #pragma unroll
    for (int o = 32; o; o >>= 1) s += __shfl_down(s, o, 64);
    __shared__ float red[4];
    if ((threadIdx.x & 63) == 0) red[threadIdx.x >> 6] = s;
    __syncthreads();
    if (threadIdx.x == 0) {
        float tot = red[0] + red[1] + red[2] + red[3];
        invn[b * 768 + c] = 1.0f / fmaxf(sqrtf(tot), 1e-12f);
    }
}

// ---------------------------------------------------------------------------
// Attention logits partials from QKT. grid (8, 64).
// ---------------------------------------------------------------------------
__global__ __launch_bounds__(256) void attn_logits_kernel(
    const bf16* __restrict__ qkt, float* __restrict__ part)
{
    const int kc = blockIdx.x;
    const int bh = blockIdx.y;
    const int b = bh >> 3, h = bh & 7;
    const int t = threadIdx.x, lane = t & 63, wv = t >> 6;
    const int lr = lane & 15, qd = lane >> 4;
    const bf16* qb = qkt + (long)b * 768 * NPIX + (long)h * 48 * NPIX;
    const bf16* kb = qb + (long)384 * NPIX;
    const int k0b = (kc * 4 + wv) * 128;
    f32x4 acc[3][3] = {};
    for (int s = 0; s < 4; s++) {
        const int k0 = k0b + s * 32;
        bf16x8 a[3], bb[3];
        #pragma unroll
        for (int i = 0; i < 3; i++) {
            a[i]  = *(const bf16x8*)(qb + (long)(i * 16 + lr) * NPIX + k0 + qd * 8);
            bb[i] = *(const bf16x8*)(kb + (long)(i * 16 + lr) * NPIX + k0 + qd * 8);
        }
        #pragma unroll
        for (int i = 0; i < 3; i++)
            #pragma unroll
            for (int j = 0; j < 3; j++)
                acc[i][j] = __builtin_amdgcn_mfma_f32_16x16x32_bf16(a[i], bb[j], acc[i][j], 0, 0, 0);
    }
    float* pp = part + ((long)bh * 32 + kc * 4 + wv) * 2304;
    #pragma unroll
    for (int i = 0; i < 3; i++)
        #pragma unroll
        for (int j = 0; j < 3; j++)
            #pragma unroll
            for (int r = 0; r < 4; r++)
                pp[(i * 16 + qd * 4 + r) * 48 + j * 16 + lr] = acc[i][j][r];
}

// Sum 32 partial slots, scale, softmax.
__global__ __launch_bounds__(256) void attn_softmax_kernel(
    const float* __restrict__ part, const float* __restrict__ invn,
    const float* __restrict__ temp, float* __restrict__ attn)
{
    __shared__ float sl[2304];
    const int bh = blockIdx.x, b = bh >> 3, h = bh & 7;
    const int t = threadIdx.x;
    const float tmp = temp[h];
    for (int idx = t; idx < 2304; idx += 256) {
        float s = 0.f;
        for (int p = 0; p < 32; p++) s += part[((long)bh * 32 + p) * 2304 + idx];
        int d = idx / 48, e = idx - d * 48;
        s *= invn[b * 768 + h * 48 + d] * invn[b * 768 + 384 + h * 48 + e] * tmp;
        sl[idx] = s;
    }
    __syncthreads();
    if (t < 48) {
        float m = -1e30f;
        #pragma unroll
        for (int e = 0; e < 48; e++) m = fmaxf(m, sl[t * 48 + e]);
        float ex[48]; float sum = 0.f;
        #pragma unroll
        for (int e = 0; e < 48; e++) { ex[e] = expf(sl[t * 48 + e] - m); sum += ex[e]; }
        float inv = 1.0f / sum;
        #pragma unroll
        for (int e = 0; e < 48; e++) attn[(long)bh * 2304 + t * 48 + e] = ex[e] * inv;
    }
}

// ---------------------------------------------------------------------------
// MFMA attention apply: at[n][h*48+d] = sum_e v[n][e] * attn[d][e].
// A = v (NHWC, e-contiguous, direct b128 global). B = attn staged in LDS as
// hi/lo bf16 pair, d-major, e padded 48->64. Per wave: 32 n rows.
// grid (32, 64): n-chunk of 128, bh.
// ---------------------------------------------------------------------------
__global__ __launch_bounds__(256) void attn_apply_kernel(
    const float* __restrict__ attn, const bf16* __restrict__ qkvt,
    bf16* __restrict__ at)
{
    __shared__ bf16 AH[48 * 64];
    __shared__ bf16 AL[48 * 64];
    const int bh = blockIdx.y, b = bh >> 3, h = bh & 7;
    const int t = threadIdx.x, lane = t & 63, wv = t >> 6;

    for (int i = t; i < 2304; i += 256) {
        int d = i / 48, e = i - d * 48;
        float a = attn[(long)bh * 2304 + i];
        bf16 hi = (bf16)a;
        AH[d * 64 + e] = hi;
        AL[d * 64 + e] = (bf16)(a - (float)hi);
    }
    for (int i = t; i < 48 * 16; i += 256) {
        int d = i >> 4, e = 48 + (i & 15);
        AH[d * 64 + e] = (bf16)0.f;
        AL[d * 64 + e] = (bf16)0.f;
    }
    __syncthreads();

    const int lr = lane & 15, qd = lane >> 4;
    const int n0 = blockIdx.x * 128 + wv * 32;
    const bf16* vbase = qkvt + (long)b * NPIX * 1152 + 768 + h * 48;

    f32x4 acc[2][3] = {};
    #pragma unroll
    for (int s = 0; s < 2; s++) {
        const int e0 = s * 32 + qd * 8;
        const bool valid = e0 < 48;
        bf16x8 bh_f[3], bl_f[3];
        #pragma unroll
        for (int j = 0; j < 3; j++) {
            bh_f[j] = *(const bf16x8*)(&AH[(j * 16 + lr) * 64 + s * 32 + qd * 8]);
            bl_f[j] = *(const bf16x8*)(&AL[(j * 16 + lr) * 64 + s * 32 + qd * 8]);
        }
        #pragma unroll
        for (int i = 0; i < 2; i++) {
            bf16x8 af = {};
            if (valid)
                af = *(const bf16x8*)(vbase + (long)(n0 + i * 16 + lr) * 1152 + e0);
            #pragma unroll
            for (int j = 0; j < 3; j++) {
                acc[i][j] = __builtin_amdgcn_mfma_f32_16x16x32_bf16(af, bh_f[j], acc[i][j], 0, 0, 0);
                acc[i][j] = __builtin_amdgcn_mfma_f32_16x16x32_bf16(af, bl_f[j], acc[i][j], 0, 0, 0);
            }
        }
    }

    bf16* ab = at + (long)b * NPIX * 384 + h * 48;
    #pragma unroll
    for (int i = 0; i < 2; i++)
        #pragma unroll
        for (int r = 0; r < 4; r++) {
            long rowOff = (long)(n0 + i * 16 + qd * 4 + r) * 384;
            #pragma unroll
            for (int j = 0; j < 3; j++)
                ab[rowOff + j * 16 + lr] = (bf16)acc[i][j][r];
        }
}

// ---------------------------------------------------------------------------
// Depthwise 3x3, pad 1, NHWC.
// ---------------------------------------------------------------------------
template<int CH>
__global__ __launch_bounds__(256) void dw3_kernel(
    const bf16* __restrict__ in, const float* __restrict__ wt,
    const float* __restrict__ bias, bf16* __restrict__ outp)
{
    constexpr int G = CH / 8;
    const int gid = blockIdx.x * 256 + threadIdx.x;
    const int p = gid / G, cg = gid - p * G;
    const int b = p >> 12, pix = p & 4095, y = pix >> 6, xx = pix & 63;

    float wr[9][8];
    #pragma unroll
    for (int e = 0; e < 8; e++)
        #pragma unroll
        for (int tp = 0; tp < 9; tp++)
            wr[tp][e] = wt[(cg * 8 + e) * 9 + tp];

    float acc[8];
    #pragma unroll
    for (int e = 0; e < 8; e++) acc[e] = bias[cg * 8 + e];

    const bf16* ib = in + ((long)b << 12) * CH;
    #pragma unroll
    for (int dy = -1; dy <= 1; dy++) {
        int yy = y + dy;
        if (yy < 0 || yy >= 64) continue;
        #pragma unroll
        for (int dx = -1; dx <= 1; dx++) {
            int x2 = xx + dx;
            if (x2 < 0 || x2 >= 64) continue;
            bf16x8 v = *(const bf16x8*)(ib + (long)(yy * 64 + x2) * CH + cg * 8);
            int tp = (dy + 1) * 3 + (dx + 1);
            #pragma unroll
            for (int e = 0; e < 8; e++) acc[e] += wr[tp][e] * (float)v[e];
        }
    }
    bf16x8 o;
    #pragma unroll
    for (int e = 0; e < 8; e++) o[e] = (bf16)acc[e];
    *(bf16x8*)(outp + (long)p * CH + cg * 8) = o;
}

// Depthwise 7x7, dil 3, pad 9, CH=64, NHWC, weights in LDS.
__global__ __launch_bounds__(256) void dw7_kernel(
    const bf16* __restrict__ in, const float* __restrict__ wt,
    const float* __restrict__ bias, bf16* __restrict__ outp)
{
    __shared__ float wf[64 * 49];
    __shared__ float bfv[64];
    for (int i = threadIdx.x; i < 64 * 49; i += 256) wf[i] = wt[i];
    if (threadIdx.x < 64) bfv[threadIdx.x] = bias[threadIdx.x];
    __syncthreads();

    const int gid = blockIdx.x * 256 + threadIdx.x;
    const int cg = gid & 7, p = gid >> 3;
    const int b = p >> 12, pix = p & 4095, y = pix >> 6, xx = pix & 63;

    float acc[8];
    #pragma unroll
    for (int e = 0; e < 8; e++) acc[e] = bfv[cg * 8 + e];

    const bf16* ib = in + ((long)b << 12) * 64;
    for (int i = 0; i < 7; i++) {
        int yy = y + i * 3 - 9;
        if (yy < 0 || yy >= 64) continue;
        for (int j = 0; j < 7; j++) {
            int x2 = xx + j * 3 - 9;
            if (x2 < 0 || x2 >= 64) continue;
            bf16x8 v = *(const bf16x8*)(ib + (long)(yy * 64 + x2) * 64 + cg * 8);
            int tp = i * 7 + j;
            #pragma unroll
            for (int e = 0; e < 8; e++) acc[e] += wf[(cg * 8 + e) * 49 + tp] * (float)v[e];
        }
    }
    bf16x8 o;
    #pragma unroll
    for (int e = 0; e < 8; e++) o[e] = (bf16)acc[e];
    *(bf16x8*)(outp + (long)p * 64 + cg * 8) = o;
}

// ---------------------------------------------------------------------------
// Two-phase column mean over NHWC.
// ---------------------------------------------------------------------------
__global__ __launch_bounds__(256) void colmean1_kernel(
    const bf16* __restrict__ in, float* __restrict__ partial, int CH)
{
    const int chunk = blockIdx.x, cb = blockIdx.y, b = blockIdx.z;
    const int c = (cb << 6) + (threadIdx.x & 63);
    const int rl = threadIdx.x >> 6;
    const bf16* base = in + ((long)b * NPIX + chunk * 128) * CH + c;
    float s = 0.f;
    for (int n = rl; n < 128; n += 4) s += (float)base[(long)n * CH];
    __shared__ float red[256];
    red[threadIdx.x] = s;
    __syncthreads();
    if (threadIdx.x < 64)
        partial[((long)(b * 32 + chunk)) * CH + (cb << 6) + threadIdx.x] =
            red[threadIdx.x] + red[threadIdx.x + 64] + red[threadIdx.x + 128] + red[threadIdx.x + 192];
}

__global__ __launch_bounds__(256) void colmean2_kernel(
    const float* __restrict__ partial, float* __restrict__ outp, int CH)
{
    int idx = blockIdx.x * 256 + threadIdx.x;
    if (idx >= 8 * CH) return;
    int b = idx / CH, c = idx - b * CH;
    float s = 0.f;
    for (int ch = 0; ch < 32; ch++) s += partial[((long)(b * 32 + ch)) * CH + c];
    outp[idx] = s * (1.0f / NPIX);
}

// ci1[b][o] = bias[o] + sum_i w[o][i]*tmean[b][i]
__global__ __launch_bounds__(64) void ci1_kernel(
    const float* __restrict__ tmean, const float* __restrict__ wt,
    const float* __restrict__ bias, float* __restrict__ ci1v)
{
    const int b = blockIdx.x, o = threadIdx.x;
    float s = bias[o];
    for (int i = 0; i < 64; i++) s += wt[o * 64 + i] * tmean[b * 64 + i];
    ci1v[b * 64 + o] = s;
}

// g[n][c] = t[n][c] * ci1[b][c] * u3[n][c]   (NHWC, CH=64)
__global__ __launch_bounds__(256) void g_eltwise_kernel(
    const bf16* __restrict__ t, const float* __restrict__ ci1v,
    const bf16* __restrict__ u3, bf16* __restrict__ g)
{
    unsigned idx = ((unsigned)blockIdx.x * 256 + threadIdx.x) << 3;
    unsigned row = idx >> 6, c0 = idx & 63;
    const float* cp = ci1v + (row >> 12) * 64 + c0;
    float4 s0 = *(const float4*)cp;
    float4 s1 = *(const float4*)(cp + 4);
    float sv[8] = {s0.x, s0.y, s0.z, s0.w, s1.x, s1.y, s1.z, s1.w};
    bf16x8 tv = *(const bf16x8*)(t + idx);
    bf16x8 uv = *(const bf16x8*)(u3 + idx);
    bf16x8 ov;
    #pragma unroll
    for (int e = 0; e < 8; e++) ov[e] = (bf16)((float)tv[e] * sv[e] * (float)uv[e]);
    *(bf16x8*)(g + idx) = ov;
}

// g2[n][c] = gelu_exact(d[n][c]) * d[n][c+96]
__global__ __launch_bounds__(256) void gelu_mul_kernel(
    const bf16* __restrict__ dd, bf16* __restrict__ g2)
{
    unsigned idx = ((unsigned)blockIdx.x * 256 + threadIdx.x) << 3;
    unsigned row = idx / 96, off = idx - row * 96;
    bf16x8 v1 = *(const bf16x8*)(dd + (long)row * 192 + off);
    bf16x8 v2 = *(const bf16x8*)(dd + (long)row * 192 + off + 96);
    bf16x8 ov;
    #pragma unroll
    for (int e = 0; e < 8; e++) {
        float x1 = (float)v1[e];
        float g = 0.5f * x1 * (1.0f + erff(x1 * 0.70710678118654752f));
        ov[e] = (bf16)(g * (float)v2[e]);
    }
    *(bf16x8*)(g2 + idx) = ov;
}

// at = (at + cmap)*sigmoid(smap) + convx*sigmoid(cm[b][c])
__global__ __launch_bounds__(256) void final_mix_kernel(
    bf16* __restrict__ at, const bf16* __restrict__ cmap,
    const bf16* __restrict__ smap, const bf16* __restrict__ convx,
    const float* __restrict__ cm)
{
    unsigned idx = ((unsigned)blockIdx.x * 256 + threadIdx.x) << 3;
    unsigned row = idx / 384, c0 = idx - row * 384;
    const float* cp = cm + (row >> 12) * 384 + c0;
    float4 s0 = *(const float4*)cp;
    float4 s1 = *(const float4*)(cp + 4);
    float gv[8] = {s0.x, s0.y, s0.z, s0.w, s1.x, s1.y, s1.z, s1.w};
    bf16x8 av = *(const bf16x8*)(at + idx);
    bf16x8 cv = *(const bf16x8*)(cmap + idx);
    bf16x8 sv = *(const bf16x8*)(smap + idx);
    bf16x8 xv = *(const bf16x8*)(convx + idx);
    bf16x8 ov;
    #pragma unroll
    for (int e = 0; e < 8; e++) {
        float a = (float)av[e] + (float)cv[e];
        float s = 1.0f / (1.0f + expf(-(float)sv[e]));
        float g = 1.0f / (1.0f + expf(-gv[e]));
        ov[e] = (bf16)(a * s + (float)xv[e] * g);
    }
    *(bf16x8*)(at + idx) = ov;
}

// ---------------------------------------------------------------------------
extern "C" void kernel_launch(void* const* d_in, const int* in_sizes, int n_in,
                              void* d_out, int out_size, void* d_ws, size_t ws_size,
                              hipStream_t stream)
{
    const int B = 8;
    const long NB = (long)B * NPIX;

    char* wsp = (char*)d_ws;
    size_t off = 0;
    auto alloc = [&](size_t bytes) -> char* {
        char* p = wsp + off; off += (bytes + 255) & ~(size_t)255; return p;
    };

    const int cvtIdx[8] = {2, 3, 5, 9, 17, 19, 21, 25};
    bf16* wcv[8];
    CvtArgs ca;
    long gpre = 0;
    for (int i = 0; i < 8; i++) {
        int ti = cvtIdx[i];
        wcv[i] = (bf16*)alloc((size_t)in_sizes[ti] * 2);
        ca.src[i] = (const float*)d_in[ti];
        ca.dst[i] = wcv[i];
        ca.gpre[i] = gpre;
        gpre += in_sizes[ti] >> 3;
    }
    ca.gpre[8] = gpre;

    const bf16 *qkv_w = wcv[0], *proj_w = wcv[1], *dw1_w = wcv[2], *cp_in_w = wcv[3],
               *ci2c_w = wcv[4], *cp_out_w = wcv[5], *sp_in_w = wcv[6], *sp_out_w = wcv[7];

    const float* xf      = (const float*)d_in[0];
    const float* temp    = (const float*)d_in[1];
    const float* proj_b  = (const float*)d_in[4];
    const float* dw1_b   = (const float*)d_in[6];
    const float* dw2_w   = (const float*)d_in[7];
    const float* dw2_b   = (const float*)d_in[8];
    const float* cp_in_b = (const float*)d_in[10];
    const float* ci1_w   = (const float*)d_in[11];
    const float* ci1_b   = (const float*)d_in[12];
    const float* ci2a_w  = (const float*)d_in[13];
    const float* ci2a_b  = (const float*)d_in[14];
    const float* ci2b_w  = (const float*)d_in[15];
    const float* ci2b_b  = (const float*)d_in[16];
    const float* ci2c_b  = (const float*)d_in[18];
    const float* cp_out_b= (const float*)d_in[20];
    const float* sp_in_b = (const float*)d_in[22];
    const float* sp_dw_w = (const float*)d_in[23];
    const float* sp_dw_b = (const float*)d_in[24];
    const float* sp_out_b= (const float*)d_in[26];

    bf16*  XT    = (bf16*) alloc(NB * 384 * 2);
    bf16*  QKVT  = (bf16*) alloc(NB * 1152 * 2);
    bf16*  AT    = (bf16*) alloc(NB * 384 * 2);
    bf16*  CONV1 = (bf16*) alloc(NB * 384 * 2);   // also first half of QKT
    bf16*  CONVX = (bf16*) alloc(NB * 384 * 2);   // also second half of QKT
    bf16*  CMAP  = (bf16*) alloc(NB * 384 * 2);
    bf16*  T     = (bf16*) alloc(NB * 64 * 2);
    bf16*  U1    = (bf16*) alloc(NB * 64 * 2);
    bf16*  U2    = (bf16*) alloc(NB * 64 * 2);
    bf16*  SP    = (bf16*) alloc(NB * 192 * 2);
    bf16*  DDb   = (bf16*) alloc(NB * 192 * 2);
    float* PART  = (float*)alloc((size_t)64 * 32 * 2304 * 4);
    float* ATTN  = (float*)alloc((size_t)64 * 2304 * 4);
    float* INVN  = (float*)alloc((size_t)B * 768 * 4);
    float* PARTM = (float*)alloc((size_t)B * 32 * 384 * 4);
    float* TMEAN = (float*)alloc((size_t)B * 64 * 4);
    float* CI1V  = (float*)alloc((size_t)B * 64 * 4);
    float* CMv   = (float*)alloc((size_t)B * 384 * 4);
    bf16* QKT  = CONV1;   // 50 MB: CONV1+CONVX contiguous; QKT dead before dw1
    bf16* SMAP = CONV1;   // CONV1 dead after dw3
    bf16* G2   = SP;      // SP dead after dw3<192>
    bf16* U3   = U1;      // U1 dead after dw7
    bf16* G    = U2;      // U2 dead after ci2c
    bf16* PRJ  = QKVT;    // QKVT dead after dw1

    // 0. weight cvt + x transpose
    cvt_kernel<<<(int)((gpre + 255) / 256), 256, 0, stream>>>(ca, gpre);
    xpose_in_kernel<<<dim3(64, 6, 8), 256, 0, stream>>>(xf, XT);

    // 1. QKVT = XT @ qkv_w^T   (B, 4096, 1152)
    gemm_bt128_kernel<<<8 * 32 * 9, 256, 0, stream>>>(
        XT, (long)NPIX * 384, 384, qkv_w, 384, nullptr, QKVT, (long)NPIX * 1152, 1152, 32);
    // 2. q,k -> NCHW copy; row norms
    qk_xpose_kernel<<<dim3(64, 12, 8), 256, 0, stream>>>(QKVT, QKT);
    rownorm_kernel<<<dim3(768, 8), 256, 0, stream>>>(QKT, INVN);
    // 3-5. attention
    attn_logits_kernel<<<dim3(8, 64), 256, 0, stream>>>(QKT, PART);
    attn_softmax_kernel<<<64, 256, 0, stream>>>(PART, INVN, temp, ATTN);
    attn_apply_kernel<<<dim3(32, 64), 256, 0, stream>>>(ATTN, QKVT, AT);
    // 6. conv1 = v @ dw1^T  (overwrites QKT low half — QKT dead)
    gemm_bt128_kernel<<<8 * 32 * 3, 256, 0, stream>>>(
        QKVT + 768, (long)NPIX * 1152, 1152, dw1_w, 384, dw1_b, CONV1, (long)NPIX * 384, 384, 32);
    // 7. conv_x = dw3x3(conv1)
    dw3_kernel<384><<<6144, 256, 0, stream>>>(CONV1, dw2_w, dw2_b, CONVX);
    // 8. t = at @ cp_in^T (M=64)
    gemm_bt64_kernel<<<8 * 32, 256, 0, stream>>>(
        AT, (long)NPIX * 384, 384, cp_in_w, 384, cp_in_b, T, (long)NPIX * 64, 64, 32);
    // 9-10. ci1
    colmean1_kernel<<<dim3(32, 1, 8), 256, 0, stream>>>(T, PARTM, 64);
    colmean2_kernel<<<2, 256, 0, stream>>>(PARTM, TMEAN, 64);
    ci1_kernel<<<8, 64, 0, stream>>>(TMEAN, ci1_w, ci1_b, CI1V);
    // 11-13. ci2 chain
    dw3_kernel<64><<<1024, 256, 0, stream>>>(T, ci2a_w, ci2a_b, U1);
    dw7_kernel<<<1024, 256, 0, stream>>>(U1, ci2b_w, ci2b_b, U2);
    gemm_bt64_kernel<<<8 * 32, 256, 0, stream>>>(
        U2, (long)NPIX * 64, 64, ci2c_w, 64, ci2c_b, U3, (long)NPIX * 64, 64, 32);
    // 14. g = t * ci1 * ci2
    g_eltwise_kernel<<<1024, 256, 0, stream>>>(T, CI1V, U3, G);
    // 15. channel_map = g @ cp_out^T (K=64)
    gemm_bt128_kernel<<<8 * 32 * 3, 256, 0, stream>>>(
        G, (long)NPIX * 64, 64, cp_out_w, 64, cp_out_b, CMAP, (long)NPIX * 384, 384, 32);
    // 16. cm = colmean(CMAP)
    colmean1_kernel<<<dim3(32, 6, 8), 256, 0, stream>>>(CMAP, PARTM, 384);
    colmean2_kernel<<<12, 256, 0, stream>>>(PARTM, CMv, 384);
    // 17. sp = conv_x @ sp_in^T (M=192)
    gemm_bt64_kernel<<<8 * 32 * 3, 256, 0, stream>>>(
        CONVX, (long)NPIX * 384, 384, sp_in_w, 384, sp_in_b, SP, (long)NPIX * 192, 192, 32);
    // 18. d = dw3x3(sp)
    dw3_kernel<192><<<3072, 256, 0, stream>>>(SP, sp_dw_w, sp_dw_b, DDb);
    // 19. g2 = gelu(x1)*x2
    gelu_mul_kernel<<<1536, 256, 0, stream>>>(DDb, G2);
    // 20. spatial_map = g2 @ sp_out^T (K=96)
    gemm_bt128_kernel<<<8 * 32 * 3, 256, 0, stream>>>(
        G2, (long)NPIX * 96, 96, sp_out_w, 96, sp_out_b, SMAP, (long)NPIX * 384, 384, 32);
    // 21. final mix (in-place on AT)
    final_mix_kernel<<<6144, 256, 0, stream>>>(AT, CMAP, SMAP, CONVX, CMv);
    // 22. prj = at @ proj_w^T
    gemm_bt128_kernel<<<8 * 32 * 3, 256, 0, stream>>>(
        AT, (long)NPIX * 384, 384, proj_w, 384, proj_b, PRJ, (long)NPIX * 384, 384, 32);
    // 23. out (B, 384, 4096) f32
    xpose_out_kernel<<<dim3(64, 6, 8), 256, 0, stream>>>(PRJ, (float*)d_out);
}

// Round 10
// 553.621 us; speedup vs baseline: 2.5325x; 1.0109x over previous
//
#include <hip/hip_runtime.h>
#include <hip/hip_bf16.h>

typedef __bf16 bf16;
typedef __bf16 bf16x4 __attribute__((ext_vector_type(4)));
typedef __bf16 bf16x8 __attribute__((ext_vector_type(8)));
typedef float f32x4 __attribute__((ext_vector_type(4)));

#define NPIX 4096

#if defined(__has_builtin)
#if __has_builtin(__builtin_amdgcn_global_load_lds)
#define HAS_GLL 1
#endif
#endif

// stage 16B per lane into LDS. GLL: base WAVE-UNIFORM; HW scatters lane*16.
__device__ __forceinline__ void stage16(const bf16* __restrict__ g, bf16* base, int lane)
{
#ifdef HAS_GLL
    __builtin_amdgcn_global_load_lds(
        (const __attribute__((address_space(1))) void*)g,
        (__attribute__((address_space(3))) void*)base, 16, 0, 0);
#else
    *(bf16x8*)(base + lane * 8) = *(const bf16x8*)g;
#endif
}

// ---------------------------------------------------------------------------
// f32 -> bf16 conversion of the 8 GEMM weight tensors.
// ---------------------------------------------------------------------------
struct CvtArgs {
    const float* src[8];
    bf16* dst[8];
    long gpre[9];
};

__global__ __launch_bounds__(256) void cvt_kernel(CvtArgs a, long totalGroups)
{
    long g = (long)blockIdx.x * 256 + threadIdx.x;
    if (g >= totalGroups) return;
    int lo = 0, hi = 7;
    while (lo < hi) { int mid = (lo + hi) >> 1; if (g >= a.gpre[mid + 1]) lo = mid + 1; else hi = mid; }
    long off = (g - a.gpre[lo]) << 3;
    const float* s = a.src[lo] + off;
    float4 v0 = *(const float4*)s;
    float4 v1 = *(const float4*)(s + 4);
    bf16x8 o;
    o[0] = (bf16)v0.x; o[1] = (bf16)v0.y; o[2] = (bf16)v0.z; o[3] = (bf16)v0.w;
    o[4] = (bf16)v1.x; o[5] = (bf16)v1.y; o[6] = (bf16)v1.z; o[7] = (bf16)v1.w;
    *(bf16x8*)(a.dst[lo] + off) = o;
}

// ---------------------------------------------------------------------------
// x (B, 384, 4096) f32  ->  XT (B, 4096, 384) bf16.
// ---------------------------------------------------------------------------
__global__ __launch_bounds__(256) void xpose_in_kernel(
    const float* __restrict__ x, bf16* __restrict__ XT)
{
    __shared__ bf16 Lt[64][72];
    const int n0 = blockIdx.x << 6, c0 = blockIdx.y << 6, b = blockIdx.z;
    const int t = threadIdx.x;
    const int rr = t >> 4, q4 = (t & 15) << 2;
    #pragma unroll
    for (int it = 0; it < 4; it++) {
        int ci = rr + it * 16;
        float4 v = *(const float4*)(x + ((long)(b * 384 + c0 + ci) << 12) + n0 + q4);
        Lt[ci][q4 + 0] = (bf16)v.x; Lt[ci][q4 + 1] = (bf16)v.y;
        Lt[ci][q4 + 2] = (bf16)v.z; Lt[ci][q4 + 3] = (bf16)v.w;
    }
    __syncthreads();
    #pragma unroll
    for (int it = 0; it < 4; it++) {
        int ni = rr + it * 16;
        bf16x4 o;
        #pragma unroll
        for (int e = 0; e < 4; e++) o[e] = Lt[q4 + e][ni];
        *(bf16x4*)(XT + ((long)(b * NPIX + n0 + ni)) * 384 + c0 + q4) = o;
    }
}

// PRJ (B, 4096, 384) bf16 -> d_out (B, 384, 4096) f32.
__global__ __launch_bounds__(256) void xpose_out_kernel(
    const bf16* __restrict__ PRJ, float* __restrict__ outp)
{
    __shared__ bf16 Lt[64][72];
    const int n0 = blockIdx.x << 6, c0 = blockIdx.y << 6, b = blockIdx.z;
    const int t = threadIdx.x;
    const int rr = t >> 4, q4 = (t & 15) << 2;
    #pragma unroll
    for (int it = 0; it < 4; it++) {
        int ni = rr + it * 16;
        bf16x4 v = *(const bf16x4*)(PRJ + ((long)(b * NPIX + n0 + ni)) * 384 + c0 + q4);
        #pragma unroll
        for (int e = 0; e < 4; e++) Lt[ni][q4 + e] = v[e];
    }
    __syncthreads();
    #pragma unroll
    for (int it = 0; it < 4; it++) {
        int ci = rr + it * 16;
        float4 f;
        f.x = (float)Lt[q4 + 0][ci]; f.y = (float)Lt[q4 + 1][ci];
        f.z = (float)Lt[q4 + 2][ci]; f.w = (float)Lt[q4 + 3][ci];
        *(float4*)(outp + ((long)(b * 384 + c0 + ci) << 12) + n0 + q4) = f;
    }
}

// QKVT cols [0,768) (q,k) NHWC -> QKT (B, 768, 4096) NCHW bf16.
__global__ __launch_bounds__(256) void qk_xpose_kernel(
    const bf16* __restrict__ qkvt, bf16* __restrict__ qkt)
{
    __shared__ bf16 Lt[64][72];
    const int n0 = blockIdx.x << 6, c0 = blockIdx.y << 6, b = blockIdx.z;
    const int t = threadIdx.x;
    const int rr = t >> 4, q4 = (t & 15) << 2;
    #pragma unroll
    for (int it = 0; it < 4; it++) {
        int ni = rr + it * 16;
        bf16x4 v = *(const bf16x4*)(qkvt + ((long)(b * NPIX + n0 + ni)) * 1152 + c0 + q4);
        #pragma unroll
        for (int e = 0; e < 4; e++) Lt[ni][q4 + e] = v[e];
    }
    __syncthreads();
    #pragma unroll
    for (int it = 0; it < 4; it++) {
        int ci = rr + it * 16;
        bf16x4 o;
        #pragma unroll
        for (int e = 0; e < 4; e++) o[e] = Lt[q4 + e][ci];
        *(bf16x4*)(qkt + ((long)(b * 768 + c0 + ci) << 12) + n0 + q4) = o;
    }
}

// ---------------------------------------------------------------------------
// BT-GEMM 128n x 128m, BKI sub-tiles of [128][32] per barrier-pair.
// ---------------------------------------------------------------------------
template<int BKI>
__global__ __launch_bounds__(256) void gemm_bt128_kernel(
    const bf16* __restrict__ Xg, long xBatch, int xRow,
    const bf16* __restrict__ Wg, int K,
    const float* __restrict__ bias, bf16* __restrict__ Og,
    long oBatch, int oRow, int nTiles)
{
    __shared__ __align__(16) bf16 At[BKI * 4096];
    __shared__ __align__(16) bf16 Bt[BKI * 4096];
    const int t = threadIdx.x;
    const int b = blockIdx.x & 7;
    const int rest = blockIdx.x >> 3;
    const int nBase = (rest % nTiles) << 7;
    const int mBase = (rest / nTiles) << 7;
    const int lane = t & 63, wv = t >> 6;
    const int nOff = (wv & 1) << 6, mOff = (wv >> 1) << 6;
    const int lr = lane & 15, qd = lane >> 4;
    const int srow = t >> 2, skb = (t & 3) << 3;
    const bf16* Ap0 = Xg + (long)b * xBatch + (long)(nBase + srow) * xRow + skb;
    const bf16* Ap1 = Ap0 + (long)64 * xRow;
    const bf16* Bp0 = Wg + (long)(mBase + srow) * K + skb;
    const bf16* Bp1 = Bp0 + (long)64 * K;

    f32x4 acc[4][4] = {};
    for (int k0 = 0; k0 < K; k0 += BKI * 32) {
        __syncthreads();
        #pragma unroll
        for (int ks = 0; ks < BKI; ks++) {
            stage16(Ap0 + k0 + ks * 32, At + ks * 4096 + wv * 512, lane);
            stage16(Ap1 + k0 + ks * 32, At + ks * 4096 + 2048 + wv * 512, lane);
            stage16(Bp0 + k0 + ks * 32, Bt + ks * 4096 + wv * 512, lane);
            stage16(Bp1 + k0 + ks * 32, Bt + ks * 4096 + 2048 + wv * 512, lane);
        }
        __syncthreads();
        #pragma unroll
        for (int ks = 0; ks < BKI; ks++) {
            bf16x8 a[4], bb[4];
            #pragma unroll
            for (int i = 0; i < 4; i++) {
                a[i]  = *(const bf16x8*)(At + ks * 4096 + (nOff + i * 16 + lr) * 32 + qd * 8);
                bb[i] = *(const bf16x8*)(Bt + ks * 4096 + (mOff + i * 16 + lr) * 32 + qd * 8);
            }
            #pragma unroll
            for (int i = 0; i < 4; i++)
                #pragma unroll
                for (int j = 0; j < 4; j++)
                    acc[i][j] = __builtin_amdgcn_mfma_f32_16x16x32_bf16(a[i], bb[j], acc[i][j], 0, 0, 0);
        }
    }

    float bj[4];
    #pragma unroll
    for (int j = 0; j < 4; j++) bj[j] = bias ? bias[mBase + mOff + j * 16 + lr] : 0.f;
    bf16* Ob = Og + (long)b * oBatch;
    #pragma unroll
    for (int i = 0; i < 4; i++)
        #pragma unroll
        for (int r = 0; r < 4; r++) {
            long rowOff = (long)(nBase + nOff + i * 16 + qd * 4 + r) * oRow;
            #pragma unroll
            for (int j = 0; j < 4; j++)
                Ob[rowOff + mBase + mOff + j * 16 + lr] = (bf16)(acc[i][j][r] + bj[j]);
        }
}

// ---------------------------------------------------------------------------
// BT-GEMM 128n x 64m, BKI sub-tiles. Optional fused out = (acc+bias)*tmul*scl.
// ---------------------------------------------------------------------------
template<int BKI>
__global__ __launch_bounds__(256) void gemm_bt64_kernel(
    const bf16* __restrict__ Xg, long xBatch, int xRow,
    const bf16* __restrict__ Wg, int K,
    const float* __restrict__ bias, bf16* __restrict__ Og,
    long oBatch, int oRow, int nTiles,
    const bf16* __restrict__ tmul, const float* __restrict__ scl)
{
    __shared__ __align__(16) bf16 At[BKI * 4096];
    __shared__ __align__(16) bf16 Bt[BKI * 2048];
    const int t = threadIdx.x;
    const int b = blockIdx.x & 7;
    const int rest = blockIdx.x >> 3;
    const int nBase = (rest % nTiles) << 7;
    const int mBase = (rest / nTiles) << 6;
    const int lane = t & 63, wv = t >> 6;
    const int nOff = wv << 5;
    const int lr = lane & 15, qd = lane >> 4;
    const int srow = t >> 2, skb = (t & 3) << 3;
    const bf16* Ap0 = Xg + (long)b * xBatch + (long)(nBase + srow) * xRow + skb;
    const bf16* Ap1 = Ap0 + (long)64 * xRow;
    const bf16* Bp0 = Wg + (long)(mBase + srow) * K + skb;

    f32x4 acc[2][4] = {};
    for (int k0 = 0; k0 < K; k0 += BKI * 32) {
        __syncthreads();
        #pragma unroll
        for (int ks = 0; ks < BKI; ks++) {
            stage16(Ap0 + k0 + ks * 32, At + ks * 4096 + wv * 512, lane);
            stage16(Ap1 + k0 + ks * 32, At + ks * 4096 + 2048 + wv * 512, lane);
            stage16(Bp0 + k0 + ks * 32, Bt + ks * 2048 + wv * 512, lane);
        }
        __syncthreads();
        #pragma unroll
        for (int ks = 0; ks < BKI; ks++) {
            bf16x8 a[2], bb[4];
            #pragma unroll
            for (int i = 0; i < 2; i++)
                a[i] = *(const bf16x8*)(At + ks * 4096 + (nOff + i * 16 + lr) * 32 + qd * 8);
            #pragma unroll
            for (int j = 0; j < 4; j++)
                bb[j] = *(const bf16x8*)(Bt + ks * 2048 + (j * 16 + lr) * 32 + qd * 8);
            #pragma unroll
            for (int i = 0; i < 2; i++)
                #pragma unroll
                for (int j = 0; j < 4; j++)
                    acc[i][j] = __builtin_amdgcn_mfma_f32_16x16x32_bf16(a[i], bb[j], acc[i][j], 0, 0, 0);
        }
    }

    float bj[4];
    #pragma unroll
    for (int j = 0; j < 4; j++) bj[j] = bias ? bias[mBase + j * 16 + lr] : 0.f;
    bf16* Ob = Og + (long)b * oBatch;
    const bf16* Tb = tmul ? (tmul + (long)b * oBatch) : nullptr;
    #pragma unroll
    for (int i = 0; i < 2; i++)
        #pragma unroll
        for (int r = 0; r < 4; r++) {
            long rowOff = (long)(nBase + nOff + i * 16 + qd * 4 + r) * oRow;
            #pragma unroll
            for (int j = 0; j < 4; j++) {
                int col = mBase + j * 16 + lr;
                float v = acc[i][j][r] + bj[j];
                if (Tb) v *= (float)Tb[rowOff + col] * scl[b * 64 + col];
                Ob[rowOff + col] = (bf16)v;
            }
        }
}

// ---------------------------------------------------------------------------
// Row inverse L2 norms over QKT (contiguous rows). grid (768, B).
// ---------------------------------------------------------------------------
__global__ __launch_bounds__(256) void rownorm_kernel(
    const bf16* __restrict__ qkt, float* __restrict__ invn)
{
    const int c = blockIdx.x, b = blockIdx.y;
    const bf16* p = qkt + ((long)b * 768 + c) * NPIX;
    float s = 0.f;
    for (int i = threadIdx.x * 8; i < NPIX; i += 2048) {
        bf16x8 v = *(const bf16x8*)(p + i);
        #pragma unroll
        for (int e = 0; e < 8; e++) { float f = (float)v[e]; s += f * f; }
    }
    #pragma unroll
    for (int o = 32; o; o >>= 1) s += __shfl_down(s, o, 64);
    __shared__ float red[4];
    if ((threadIdx.x & 63) == 0) red[threadIdx.x >> 6] = s;
    __syncthreads();
    if (threadIdx.x == 0) {
        float tot = red[0] + red[1] + red[2] + red[3];
        invn[b * 768 + c] = 1.0f / fmaxf(sqrtf(tot), 1e-12f);
    }
}

// ---------------------------------------------------------------------------
// Attention logits partials from QKT. grid (8, 64).
// ---------------------------------------------------------------------------
__global__ __launch_bounds__(256) void attn_logits_kernel(
    const bf16* __restrict__ qkt, float* __restrict__ part)
{
    const int kc = blockIdx.x;
    const int bh = blockIdx.y;
    const int b = bh >> 3, h = bh & 7;
    const int t = threadIdx.x, lane = t & 63, wv = t >> 6;
    const int lr = lane & 15, qd = lane >> 4;
    const bf16* qb = qkt + (long)b * 768 * NPIX + (long)h * 48 * NPIX;
    const bf16* kb = qb + (long)384 * NPIX;
    const int k0b = (kc * 4 + wv) * 128;
    f32x4 acc[3][3] = {};
    for (int s = 0; s < 4; s++) {
        const int k0 = k0b + s * 32;
        bf16x8 a[3], bb[3];
        #pragma unroll
        for (int i = 0; i < 3; i++) {
            a[i]  = *(const bf16x8*)(qb + (long)(i * 16 + lr) * NPIX + k0 + qd * 8);
            bb[i] = *(const bf16x8*)(kb + (long)(i * 16 + lr) * NPIX + k0 + qd * 8);
        }
        #pragma unroll
        for (int i = 0; i < 3; i++)
            #pragma unroll
            for (int j = 0; j < 3; j++)
                acc[i][j] = __builtin_amdgcn_mfma_f32_16x16x32_bf16(a[i], bb[j], acc[i][j], 0, 0, 0);
    }
    float* pp = part + ((long)bh * 32 + kc * 4 + wv) * 2304;
    #pragma unroll
    for (int i = 0; i < 3; i++)
        #pragma unroll
        for (int j = 0; j < 3; j++)
            #pragma unroll
            for (int r = 0; r < 4; r++)
                pp[(i * 16 + qd * 4 + r) * 48 + j * 16 + lr] = acc[i][j][r];
}

// Sum 32 partial slots, scale, softmax.
__global__ __launch_bounds__(256) void attn_softmax_kernel(
    const float* __restrict__ part, const float* __restrict__ invn,
    const float* __restrict__ temp, float* __restrict__ attn)
{
    __shared__ float sl[2304];
    const int bh = blockIdx.x, b = bh >> 3, h = bh & 7;
    const int t = threadIdx.x;
    const float tmp = temp[h];
    for (int idx = t; idx < 2304; idx += 256) {
        float s = 0.f;
        for (int p = 0; p < 32; p++) s += part[((long)bh * 32 + p) * 2304 + idx];
        int d = idx / 48, e = idx - d * 48;
        s *= invn[b * 768 + h * 48 + d] * invn[b * 768 + 384 + h * 48 + e] * tmp;
        sl[idx] = s;
    }
    __syncthreads();
    if (t < 48) {
        float m = -1e30f;
        #pragma unroll
        for (int e = 0; e < 48; e++) m = fmaxf(m, sl[t * 48 + e]);
        float ex[48]; float sum = 0.f;
        #pragma unroll
        for (int e = 0; e < 48; e++) { ex[e] = expf(sl[t * 48 + e] - m); sum += ex[e]; }
        float inv = 1.0f / sum;
        #pragma unroll
        for (int e = 0; e < 48; e++) attn[(long)bh * 2304 + t * 48 + e] = ex[e] * inv;
    }
}

// ---------------------------------------------------------------------------
// MFMA attention apply: at[n][h*48+d] = sum_e v[n][e]*attn[d][e]. grid (32,64).
// v read from QKVT NHWC (+768 offset, stride 1152).
// ---------------------------------------------------------------------------
__global__ __launch_bounds__(256) void attn_apply_kernel(
    const float* __restrict__ attn, const bf16* __restrict__ qkvt,
    bf16* __restrict__ at)
{
    __shared__ bf16 AH[48 * 64];
    __shared__ bf16 AL[48 * 64];
    const int bh = blockIdx.y, b = bh >> 3, h = bh & 7;
    const int t = threadIdx.x, lane = t & 63, wv = t >> 6;

    for (int i = t; i < 2304; i += 256) {
        int d = i / 48, e = i - d * 48;
        float a = attn[(long)bh * 2304 + i];
        bf16 hi = (bf16)a;
        AH[d * 64 + e] = hi;
        AL[d * 64 + e] = (bf16)(a - (float)hi);
    }
    for (int i = t; i < 48 * 16; i += 256) {
        int d = i >> 4, e = 48 + (i & 15);
        AH[d * 64 + e] = (bf16)0.f;
        AL[d * 64 + e] = (bf16)0.f;
    }
    __syncthreads();

    const int lr = lane & 15, qd = lane >> 4;
    const int n0 = blockIdx.x * 128 + wv * 32;
    const bf16* vbase = qkvt + (long)b * NPIX * 1152 + 768 + h * 48;

    f32x4 acc[2][3] = {};
    #pragma unroll
    for (int s = 0; s < 2; s++) {
        const int e0 = s * 32 + qd * 8;
        const bool valid = e0 < 48;
        bf16x8 bh_f[3], bl_f[3];
        #pragma unroll
        for (int j = 0; j < 3; j++) {
            bh_f[j] = *(const bf16x8*)(&AH[(j * 16 + lr) * 64 + s * 32 + qd * 8]);
            bl_f[j] = *(const bf16x8*)(&AL[(j * 16 + lr) * 64 + s * 32 + qd * 8]);
        }
        #pragma unroll
        for (int i = 0; i < 2; i++) {
            bf16x8 af = {};
            if (valid)
                af = *(const bf16x8*)(vbase + (long)(n0 + i * 16 + lr) * 1152 + e0);
            #pragma unroll
            for (int j = 0; j < 3; j++) {
                acc[i][j] = __builtin_amdgcn_mfma_f32_16x16x32_bf16(af, bh_f[j], acc[i][j], 0, 0, 0);
                acc[i][j] = __builtin_amdgcn_mfma_f32_16x16x32_bf16(af, bl_f[j], acc[i][j], 0, 0, 0);
            }
        }
    }

    bf16* ab = at + (long)b * NPIX * 384 + h * 48;
    #pragma unroll
    for (int i = 0; i < 2; i++)
        #pragma unroll
        for (int r = 0; r < 4; r++) {
            long rowOff = (long)(n0 + i * 16 + qd * 4 + r) * 384;
            #pragma unroll
            for (int j = 0; j < 3; j++)
                ab[rowOff + j * 16 + lr] = (bf16)acc[i][j][r];
        }
}

// ---------------------------------------------------------------------------
// Depthwise 3x3, pad 1, NHWC.
// ---------------------------------------------------------------------------
template<int CH>
__global__ __launch_bounds__(256) void dw3_kernel(
    const bf16* __restrict__ in, const float* __restrict__ wt,
    const float* __restrict__ bias, bf16* __restrict__ outp)
{
    constexpr int G = CH / 8;
    const int gid = blockIdx.x * 256 + threadIdx.x;
    const int p = gid / G, cg = gid - p * G;
    const int b = p >> 12, pix = p & 4095, y = pix >> 6, xx = pix & 63;

    float wr[9][8];
    #pragma unroll
    for (int e = 0; e < 8; e++)
        #pragma unroll
        for (int tp = 0; tp < 9; tp++)
            wr[tp][e] = wt[(cg * 8 + e) * 9 + tp];

    float acc[8];
    #pragma unroll
    for (int e = 0; e < 8; e++) acc[e] = bias[cg * 8 + e];

    const bf16* ib = in + ((long)b << 12) * CH;
    #pragma unroll
    for (int dy = -1; dy <= 1; dy++) {
        int yy = y + dy;
        if (yy < 0 || yy >= 64) continue;
        #pragma unroll
        for (int dx = -1; dx <= 1; dx++) {
            int x2 = xx + dx;
            if (x2 < 0 || x2 >= 64) continue;
            bf16x8 v = *(const bf16x8*)(ib + (long)(yy * 64 + x2) * CH + cg * 8);
            int tp = (dy + 1) * 3 + (dx + 1);
            #pragma unroll
            for (int e = 0; e < 8; e++) acc[e] += wr[tp][e] * (float)v[e];
        }
    }
    bf16x8 o;
    #pragma unroll
    for (int e = 0; e < 8; e++) o[e] = (bf16)acc[e];
    *(bf16x8*)(outp + (long)p * CH + cg * 8) = o;
}

// Depthwise 7x7, dil 3, pad 9, CH=64, NHWC, weights in LDS.
__global__ __launch_bounds__(256) void dw7_kernel(
    const bf16* __restrict__ in, const float* __restrict__ wt,
    const float* __restrict__ bias, bf16* __restrict__ outp)
{
    __shared__ float wf[64 * 49];
    __shared__ float bfv[64];
    for (int i = threadIdx.x; i < 64 * 49; i += 256) wf[i] = wt[i];
    if (threadIdx.x < 64) bfv[threadIdx.x] = bias[threadIdx.x];
    __syncthreads();

    const int gid = blockIdx.x * 256 + threadIdx.x;
    const int cg = gid & 7, p = gid >> 3;
    const int b = p >> 12, pix = p & 4095, y = pix >> 6, xx = pix & 63;

    float acc[8];
    #pragma unroll
    for (int e = 0; e < 8; e++) acc[e] = bfv[cg * 8 + e];

    const bf16* ib = in + ((long)b << 12) * 64;
    for (int i = 0; i < 7; i++) {
        int yy = y + i * 3 - 9;
        if (yy < 0 || yy >= 64) continue;
        for (int j = 0; j < 7; j++) {
            int x2 = xx + j * 3 - 9;
            if (x2 < 0 || x2 >= 64) continue;
            bf16x8 v = *(const bf16x8*)(ib + (long)(yy * 64 + x2) * 64 + cg * 8);
            int tp = i * 7 + j;
            #pragma unroll
            for (int e = 0; e < 8; e++) acc[e] += wf[(cg * 8 + e) * 49 + tp] * (float)v[e];
        }
    }
    bf16x8 o;
    #pragma unroll
    for (int e = 0; e < 8; e++) o[e] = (bf16)acc[e];
    *(bf16x8*)(outp + (long)p * 64 + cg * 8) = o;
}

// ---------------------------------------------------------------------------
// Two-phase column mean over NHWC.
// ---------------------------------------------------------------------------
__global__ __launch_bounds__(256) void colmean1_kernel(
    const bf16* __restrict__ in, float* __restrict__ partial, int CH)
{
    const int chunk = blockIdx.x, cb = blockIdx.y, b = blockIdx.z;
    const int c = (cb << 6) + (threadIdx.x & 63);
    const int rl = threadIdx.x >> 6;
    const bf16* base = in + ((long)b * NPIX + chunk * 128) * CH + c;
    float s = 0.f;
    for (int n = rl; n < 128; n += 4) s += (float)base[(long)n * CH];
    __shared__ float red[256];
    red[threadIdx.x] = s;
    __syncthreads();
    if (threadIdx.x < 64)
        partial[((long)(b * 32 + chunk)) * CH + (cb << 6) + threadIdx.x] =
            red[threadIdx.x] + red[threadIdx.x + 64] + red[threadIdx.x + 128] + red[threadIdx.x + 192];
}

__global__ __launch_bounds__(256) void colmean2_kernel(
    const float* __restrict__ partial, float* __restrict__ outp, int CH)
{
    int idx = blockIdx.x * 256 + threadIdx.x;
    if (idx >= 8 * CH) return;
    int b = idx / CH, c = idx - b * CH;
    float s = 0.f;
    for (int ch = 0; ch < 32; ch++) s += partial[((long)(b * 32 + ch)) * CH + c];
    outp[idx] = s * (1.0f / NPIX);
}

// ci1[b][o] = bias[o] + sum_i w[o][i]*tmean[b][i]
__global__ __launch_bounds__(64) void ci1_kernel(
    const float* __restrict__ tmean, const float* __restrict__ wt,
    const float* __restrict__ bias, float* __restrict__ ci1v)
{
    const int b = blockIdx.x, o = threadIdx.x;
    float s = bias[o];
    for (int i = 0; i < 64; i++) s += wt[o * 64 + i] * tmean[b * 64 + i];
    ci1v[b * 64 + o] = s;
}

// g2[n][c] = gelu_exact(d[n][c]) * d[n][c+96]
__global__ __launch_bounds__(256) void gelu_mul_kernel(
    const bf16* __restrict__ dd, bf16* __restrict__ g2)
{
    unsigned idx = ((unsigned)blockIdx.x * 256 + threadIdx.x) << 3;
    unsigned row = idx / 96, off = idx - row * 96;
    bf16x8 v1 = *(const bf16x8*)(dd + (long)row * 192 + off);
    bf16x8 v2 = *(const bf16x8*)(dd + (long)row * 192 + off + 96);
    bf16x8 ov;
    #pragma unroll
    for (int e = 0; e < 8; e++) {
        float x1 = (float)v1[e];
        float g = 0.5f * x1 * (1.0f + erff(x1 * 0.70710678118654752f));
        ov[e] = (bf16)(g * (float)v2[e]);
    }
    *(bf16x8*)(g2 + idx) = ov;
}

// at = (at + cmap)*sigmoid(smap) + convx*sigmoid(cm[b][c])
__global__ __launch_bounds__(256) void final_mix_kernel(
    bf16* __restrict__ at, const bf16* __restrict__ cmap,
    const bf16* __restrict__ smap, const bf16* __restrict__ convx,
    const float* __restrict__ cm)
{
    unsigned idx = ((unsigned)blockIdx.x * 256 + threadIdx.x) << 3;
    unsigned row = idx / 384, c0 = idx - row * 384;
    const float* cp = cm + (row >> 12) * 384 + c0;
    float4 s0 = *(const float4*)cp;
    float4 s1 = *(const float4*)(cp + 4);
    float gv[8] = {s0.x, s0.y, s0.z, s0.w, s1.x, s1.y, s1.z, s1.w};
    bf16x8 av = *(const bf16x8*)(at + idx);
    bf16x8 cv = *(const bf16x8*)(cmap + idx);
    bf16x8 sv = *(const bf16x8*)(smap + idx);
    bf16x8 xv = *(const bf16x8*)(convx + idx);
    bf16x8 ov;
    #pragma unroll
    for (int e = 0; e < 8; e++) {
        float a = (float)av[e] + (float)cv[e];
        float s = 1.0f / (1.0f + expf(-(float)sv[e]));
        float g = 1.0f / (1.0f + expf(-gv[e]));
        ov[e] = (bf16)(a * s + (float)xv[e] * g);
    }
    *(bf16x8*)(at + idx) = ov;
}

// ---------------------------------------------------------------------------
extern "C" void kernel_launch(void* const* d_in, const int* in_sizes, int n_in,
                              void* d_out, int out_size, void* d_ws, size_t ws_size,
                              hipStream_t stream)
{
    const int B = 8;
    const long NB = (long)B * NPIX;

    char* wsp = (char*)d_ws;
    size_t off = 0;
    auto alloc = [&](size_t bytes) -> char* {
        char* p = wsp + off; off += (bytes + 255) & ~(size_t)255; return p;
    };

    const int cvtIdx[8] = {2, 3, 5, 9, 17, 19, 21, 25};
    bf16* wcv[8];
    CvtArgs ca;
    long gpre = 0;
    for (int i = 0; i < 8; i++) {
        int ti = cvtIdx[i];
        wcv[i] = (bf16*)alloc((size_t)in_sizes[ti] * 2);
        ca.src[i] = (const float*)d_in[ti];
        ca.dst[i] = wcv[i];
        ca.gpre[i] = gpre;
        gpre += in_sizes[ti] >> 3;
    }
    ca.gpre[8] = gpre;

    const bf16 *qkv_w = wcv[0], *proj_w = wcv[1], *dw1_w = wcv[2], *cp_in_w = wcv[3],
               *ci2c_w = wcv[4], *cp_out_w = wcv[5], *sp_in_w = wcv[6], *sp_out_w = wcv[7];

    const float* xf      = (const float*)d_in[0];
    const float* temp    = (const float*)d_in[1];
    const float* proj_b  = (const float*)d_in[4];
    const float* dw1_b   = (const float*)d_in[6];
    const float* dw2_w   = (const float*)d_in[7];
    const float* dw2_b   = (const float*)d_in[8];
    const float* cp_in_b = (const float*)d_in[10];
    const float* ci1_w   = (const float*)d_in[11];
    const float* ci1_b   = (const float*)d_in[12];
    const float* ci2a_w  = (const float*)d_in[13];
    const float* ci2a_b  = (const float*)d_in[14];
    const float* ci2b_w  = (const float*)d_in[15];
    const float* ci2b_b  = (const float*)d_in[16];
    const float* ci2c_b  = (const float*)d_in[18];
    const float* cp_out_b= (const float*)d_in[20];
    const float* sp_in_b = (const float*)d_in[22];
    const float* sp_dw_w = (const float*)d_in[23];
    const float* sp_dw_b = (const float*)d_in[24];
    const float* sp_out_b= (const float*)d_in[26];

    bf16*  XT    = (bf16*) alloc(NB * 384 * 2);
    bf16*  QKVT  = (bf16*) alloc(NB * 1152 * 2);
    bf16*  AT    = (bf16*) alloc(NB * 384 * 2);
    bf16*  CONV1 = (bf16*) alloc(NB * 384 * 2);   // also first half of QKT
    bf16*  CONVX = (bf16*) alloc(NB * 384 * 2);   // also second half of QKT
    bf16*  CMAP  = (bf16*) alloc(NB * 384 * 2);
    bf16*  T     = (bf16*) alloc(NB * 64 * 2);
    bf16*  U1    = (bf16*) alloc(NB * 64 * 2);
    bf16*  U2    = (bf16*) alloc(NB * 64 * 2);
    bf16*  SP    = (bf16*) alloc(NB * 192 * 2);
    bf16*  DDb   = (bf16*) alloc(NB * 192 * 2);
    float* PART  = (float*)alloc((size_t)64 * 32 * 2304 * 4);
    float* ATTN  = (float*)alloc((size_t)64 * 2304 * 4);
    float* INVN  = (float*)alloc((size_t)B * 768 * 4);
    float* PARTM = (float*)alloc((size_t)B * 32 * 384 * 4);
    float* TMEAN = (float*)alloc((size_t)B * 64 * 4);
    float* CI1V  = (float*)alloc((size_t)B * 64 * 4);
    float* CMv   = (float*)alloc((size_t)B * 384 * 4);
    bf16* QKT  = CONV1;   // 50 MB: CONV1+CONVX contiguous; QKT dead before dw1
    bf16* SMAP = CONV1;   // CONV1 dead after dw3<384>
    bf16* G2   = SP;      // SP dead after dw3<192>
    bf16* G    = U1;      // U1 dead after dw7; ci2c reads U2, writes G=U1
    bf16* PRJ  = QKVT;    // QKVT dead after dw1

    // 0. weight cvt + x transpose
    cvt_kernel<<<(int)((gpre + 255) / 256), 256, 0, stream>>>(ca, gpre);
    xpose_in_kernel<<<dim3(64, 6, 8), 256, 0, stream>>>(xf, XT);

    // 1. QKVT = XT @ qkv_w^T   (B, 4096, 1152)
    gemm_bt128_kernel<2><<<8 * 32 * 9, 256, 0, stream>>>(
        XT, (long)NPIX * 384, 384, qkv_w, 384, nullptr, QKVT, (long)NPIX * 1152, 1152, 32);
    // 2. q,k -> NCHW copy; row norms
    qk_xpose_kernel<<<dim3(64, 12, 8), 256, 0, stream>>>(QKVT, QKT);
    rownorm_kernel<<<dim3(768, 8), 256, 0, stream>>>(QKT, INVN);
    // 3-5. attention
    attn_logits_kernel<<<dim3(8, 64), 256, 0, stream>>>(QKT, PART);
    attn_softmax_kernel<<<64, 256, 0, stream>>>(PART, INVN, temp, ATTN);
    attn_apply_kernel<<<dim3(32, 64), 256, 0, stream>>>(ATTN, QKVT, AT);
    // 6. conv1 = v @ dw1^T  (overwrites QKT low half — QKT dead)
    gemm_bt128_kernel<2><<<8 * 32 * 3, 256, 0, stream>>>(
        QKVT + 768, (long)NPIX * 1152, 1152, dw1_w, 384, dw1_b, CONV1, (long)NPIX * 384, 384, 32);
    // 7. conv_x = dw3x3(conv1)
    dw3_kernel<384><<<6144, 256, 0, stream>>>(CONV1, dw2_w, dw2_b, CONVX);
    // 8. t = at @ cp_in^T (M=64)
    gemm_bt64_kernel<2><<<8 * 32, 256, 0, stream>>>(
        AT, (long)NPIX * 384, 384, cp_in_w, 384, cp_in_b, T, (long)NPIX * 64, 64, 32,
        nullptr, nullptr);
    // 9-10. ci1
    colmean1_kernel<<<dim3(32, 1, 8), 256, 0, stream>>>(T, PARTM, 64);
    colmean2_kernel<<<2, 256, 0, stream>>>(PARTM, TMEAN, 64);
    ci1_kernel<<<8, 64, 0, stream>>>(TMEAN, ci1_w, ci1_b, CI1V);
    // 11-13. ci2 chain; ci2c fused with g = t * ci1 * (acc+bias)
    dw3_kernel<64><<<1024, 256, 0, stream>>>(T, ci2a_w, ci2a_b, U1);
    dw7_kernel<<<1024, 256, 0, stream>>>(U1, ci2b_w, ci2b_b, U2);
    gemm_bt64_kernel<2><<<8 * 32, 256, 0, stream>>>(
        U2, (long)NPIX * 64, 64, ci2c_w, 64, ci2c_b, G, (long)NPIX * 64, 64, 32,
        T, CI1V);
    // 14. channel_map = g @ cp_out^T (K=64)
    gemm_bt128_kernel<2><<<8 * 32 * 3, 256, 0, stream>>>(
        G, (long)NPIX * 64, 64, cp_out_w, 64, cp_out_b, CMAP, (long)NPIX * 384, 384, 32);
    // 15. cm = colmean(CMAP)
    colmean1_kernel<<<dim3(32, 6, 8), 256, 0, stream>>>(CMAP, PARTM, 384);
    colmean2_kernel<<<12, 256, 0, stream>>>(PARTM, CMv, 384);
    // 16. sp = conv_x @ sp_in^T (M=192)
    gemm_bt64_kernel<2><<<8 * 32 * 3, 256, 0, stream>>>(
        CONVX, (long)NPIX * 384, 384, sp_in_w, 384, sp_in_b, SP, (long)NPIX * 192, 192, 32,
        nullptr, nullptr);
    // 17. d = dw3x3(sp)
    dw3_kernel<192><<<3072, 256, 0, stream>>>(SP, sp_dw_w, sp_dw_b, DDb);
    // 18. g2 = gelu(x1)*x2
    gelu_mul_kernel<<<1536, 256, 0, stream>>>(DDb, G2);
    // 19. spatial_map = g2 @ sp_out^T (K=96 -> BKI=1)
    gemm_bt128_kernel<1><<<8 * 32 * 3, 256, 0, stream>>>(
        G2, (long)NPIX * 96, 96, sp_out_w, 96, sp_out_b, SMAP, (long)NPIX * 384, 384, 32);
    // 20. final mix (in-place on AT)
    final_mix_kernel<<<6144, 256, 0, stream>>>(AT, CMAP, SMAP, CONVX, CMv);
    // 21. prj = at @ proj_w^T
    gemm_bt128_kernel<2><<<8 * 32 * 3, 256, 0, stream>>>(
        AT, (long)NPIX * 384, 384, proj_w, 384, proj_b, PRJ, (long)NPIX * 384, 384, 32);
    // 22. out (B, 384, 4096) f32
    xpose_out_kernel<<<dim3(64, 6, 8), 256, 0, stream>>>(PRJ, (float*)d_out);
}